// Round 11
// baseline (303.643 us; speedup 1.0000x reference)
//
#include <hip/hip_runtime.h>
#include <hip/hip_fp16.h>
#include <hip/hip_bf16.h>

// ---------------------------------------------------------------------------
// EncoderLayer (MatNet mixed-score MHA) for MI355X — R11.
// R11 = R10 + per-head-packed q/k layouts (q_pack[tile][h][r][d16],
// k_pack[b][h][c][d16]) written by the QKV GEMM epilogue, making all QK^T
// fragment loads 512 B-contiguous per wave (R10: 32 B @ 512 B stride ->
// 72.8 MB FETCH, memory-bound attn).
// Inputs f32, masks int32, d_out f32. Row-space: ope[0,8192) veh[8192,9216)
// ma1[9216,11264) ma2[11264,13312).
// ---------------------------------------------------------------------------

typedef unsigned short u16;
typedef __attribute__((ext_vector_type(8))) short bf16x8;
typedef __attribute__((ext_vector_type(4))) float f32x4;
struct us4 { u16 x, y, z, w; };

__device__ __forceinline__ float bf2f(u16 u) {
  return __uint_as_float(((unsigned int)u) << 16);
}
__device__ __forceinline__ u16 f2bf(float f) {
  unsigned int x = __float_as_uint(f);
  x += 0x7FFFu + ((x >> 16) & 1u);
  return (u16)(x >> 16);
}
// packed fp16 max (ROCm 7.2 lacks the __half2 __hmax2 overload on gfx950)
__device__ __forceinline__ __half2 h2max(__half2 a, __half2 b) {
  unsigned au = *(unsigned*)&a, bu = *(unsigned*)&b, ru;
  asm("v_pk_max_f16 %0, %1, %2" : "=v"(ru) : "v"(au), "v"(bu));
  return *(__half2*)&ru;
}

#define NBATCH 16
#define NOPE   512
#define NMA    128
#define NVEH   64
#define EDIM   256

// ---------------------------------------------------------------------------
// Grouped prep: [0,2816) f32->bf16 converts; [2816,6912) aproc (2 rows/blk);
// [6912,6928) aoff; [6928,6944) aon.
// ---------------------------------------------------------------------------
struct PrepArgs {
  const float* ope; const float* ma; const float* veh;
  u16* ope_bf; u16* ma_bf; u16* veh_bf;
  const float* proc; const int* mask_dyn; float* A_proc;
  const float* mv; float* A_offb;
  const float* trans; const int* mask_ma; float* A_on; float* A_pcing;
};
__global__ __launch_bounds__(256) void prep_grouped(PrepArgs a) {
  int blk = blockIdx.x, t = threadIdx.x;
  if (blk < 2816) {
    int i = blk * 256 + t;
    const float* s; u16* d; int j;
    if (i < 524288)      { s = a.ope; d = a.ope_bf; j = i; }
    else if (i < 655360) { s = a.ma;  d = a.ma_bf;  j = i - 524288; }
    else                 { s = a.veh; d = a.veh_bf; j = i - 655360; }
    float4 v = ((const float4*)s)[j];
    us4 o = { f2bf(v.x), f2bf(v.y), f2bf(v.z), f2bf(v.w) };
    ((us4*)d)[j] = o;
    return;
  }
  if (blk < 6912) {
    int local = blk - 2816;
    int row = local * 2 + (t >> 7);
    int lane = t & 127;
    size_t idx = (size_t)row * NMA + lane;
    float av = a.mask_dyn[idx] ? a.proc[idx] : 0.0f;
    float cand = (av != 0.0f) ? av : 1.0e30f;
    __shared__ float red[256];
    red[t] = cand;
    __syncthreads();
    for (int s = 64; s > 0; s >>= 1) {
      if (lane < s) red[t] = fminf(red[t], red[t + s]);
      __syncthreads();
    }
    float mn = red[t & 128];
    a.A_proc[idx] = (av != 0.0f && av == mn) ? 1.0f : 0.0f;
    return;
  }
  if (blk < 6928) {
    int b = blk - 6912;
    const int n = NVEH * NMA;
    const float* xb = a.mv + (size_t)b * n;
    float mn = 1.0e30f, mx = -1.0e30f;
    for (int i = t; i < n; i += 256) {
      float v = xb[i];
      mn = fminf(mn, v);
      mx = fmaxf(mx, v);
    }
    __shared__ float smn[256], smx[256];
    smn[t] = mn; smx[t] = mx;
    __syncthreads();
    for (int s = 128; s > 0; s >>= 1) {
      if (t < s) {
        smn[t] = fminf(smn[t], smn[t + s]);
        smx[t] = fmaxf(smx[t], smx[t + s]);
      }
      __syncthreads();
    }
    float lo = smn[0], inv = 1.0f / (smx[0] - smn[0]);
    for (int i = t; i < n; i += 256)
      a.A_offb[(size_t)b * n + i] = 1.0f - (xb[i] - lo) * inv;
    return;
  }
  {
    int b = blk - 6928;
    __shared__ unsigned char mrow[NMA];
    if (t < NMA) mrow[t] = (unsigned char)(a.mask_ma[(size_t)b * NMA + t] != 0);
    __syncthreads();
    const float* tb = a.trans + (size_t)b * NMA * NMA;
    float mn = 1.0e30f, mx = -1.0e30f;
    for (int idx = t; idx < NMA * NMA; idx += 256) {
      int i = idx >> 7, j = idx & 127;
      bool m2 = mrow[i] && mrow[j];
      float tt = m2 ? tb[idx] : 101.0f;
      mn = fminf(mn, tt);
      mx = fmaxf(mx, tt);
    }
    __shared__ float smn[256], smx[256];
    smn[t] = mn; smx[t] = mx;
    __syncthreads();
    for (int s = 128; s > 0; s >>= 1) {
      if (t < s) {
        smn[t] = fminf(smn[t], smn[t + s]);
        smx[t] = fmaxf(smx[t], smx[t + s]);
      }
      __syncthreads();
    }
    float lo = smn[0], inv = 1.0f / (smx[0] - smn[0]);
    for (int idx = t; idx < NMA * NMA; idx += 256) {
      int i = idx >> 7, j = idx & 127;
      bool m2 = mrow[i] && mrow[j];
      float tt = m2 ? tb[idx] : 101.0f;
      a.A_on[(size_t)b * NMA * NMA + idx] = 1.0f - (tt - lo) * inv;
      a.A_pcing[(size_t)b * NMA * NMA + idx] = m2 ? 0.0f : 1.0f;
    }
  }
}

// ---------------------------------------------------------------------------
// Merged weight transposes: f32 [Kd][Nd] -> bf16 [Nd][Kd], 32x32 tiles.
// ---------------------------------------------------------------------------
struct TrArgs {
  const float* Wq; const float* Wk; const float* Wv; const float* Wo;
  const float* ffW1; const float* ffW2; const float* maproj;
  u16* WqT; u16* WkT; u16* WvT; u16* WoT; u16* ffW1T; u16* ffW2T; u16* maprojT;
};
__global__ __launch_bounds__(256) void transpose_all(TrArgs a) {
  int blk = blockIdx.x;
  const float* src; u16* dst; int Kd, Nd, tile;
  if (blk < 1024) {
    int w = blk >> 8, i = (blk >> 6) & 3; tile = blk & 63;
    const float* sw = (w == 0 ? a.Wq : w == 1 ? a.Wk : w == 2 ? a.Wv : a.Wo);
    u16* dw = (w == 0 ? a.WqT : w == 1 ? a.WkT : w == 2 ? a.WvT : a.WoT);
    src = sw + (size_t)i * 65536; dst = dw + (size_t)i * 65536;
    Kd = 256; Nd = 256;
  } else if (blk < 1536) {
    int z = (blk - 1024) >> 7; tile = (blk - 1024) & 127;
    src = a.ffW1 + (size_t)z * 131072; dst = a.ffW1T + (size_t)z * 131072;
    Kd = 256; Nd = 512;
  } else {
    int z = (blk - 1536) >> 7; tile = (blk - 1536) & 127;
    if (z < 4) { src = a.ffW2 + (size_t)z * 131072; dst = a.ffW2T + (size_t)z * 131072; }
    else       { src = a.maproj; dst = a.maprojT; }
    Kd = 512; Nd = 256;
  }
  int nx = Nd >> 5;
  int k0 = (tile / nx) * 32, n0 = (tile % nx) * 32;
  __shared__ float tl[32][33];
  int tx = threadIdx.x & 31, ty = threadIdx.x >> 5;
#pragma unroll
  for (int r = 0; r < 4; r++)
    tl[ty + r * 8][tx] = src[(size_t)(k0 + ty + r * 8) * Nd + n0 + tx];
  __syncthreads();
#pragma unroll
  for (int r = 0; r < 4; r++)
    dst[(size_t)(n0 + ty + r * 8) * Kd + k0 + tx] = f2bf(tl[tx][ty + r * 8]);
}

// ---------------------------------------------------------------------------
// v_all [4][16 b][128 c][256 d] -> vT_all [4][16 b][256 d][128 c], bf16.
// ---------------------------------------------------------------------------
__global__ __launch_bounds__(256) void transpose_v(
    const u16* __restrict__ src, u16* __restrict__ dst) {
  int g = blockIdx.z >> 4, b = blockIdx.z & 15;
  int d0 = blockIdx.x * 32, c0 = blockIdx.y * 32;
  __shared__ u16 tile[32][33];
  int tx = threadIdx.x & 31, ty = threadIdx.x >> 5;
  const u16* s = src + ((size_t)g * 16 + b) * 32768;
  u16* d = dst + ((size_t)g * 16 + b) * 32768;
#pragma unroll
  for (int r = 0; r < 4; r++)
    tile[ty + r * 8][tx] = s[(size_t)(c0 + ty + r * 8) * 256 + d0 + tx];
  __syncthreads();
#pragma unroll
  for (int r = 0; r < 4; r++)
    d[(size_t)(d0 + ty + r * 8) * 128 + c0 + tx] = tile[tx][ty + r * 8];
}

// ---------------------------------------------------------------------------
// Grouped MFMA GEMM. mode: 0 = row-major C, 1 = q-pack C[tile][h][r][d16],
// 2 = k-pack C[b][h][c][d16] (per-head-contiguous for attn frag loads).
// ---------------------------------------------------------------------------
struct GG {
  const u16* A; const u16* WT; const float* bias; u16* C;
  int M, N, K, epi, wgStart, wgCols, mode;
};
struct GGArgs { GG g[12]; int n; };

__global__ __launch_bounds__(256) void gemm_grouped(GGArgs args) {
  int wg = blockIdx.x;
  int gi = 0;
  for (int i = 1; i < args.n; i++)
    if (wg >= args.g[i].wgStart) gi = i;
  GG gg = args.g[gi];
  int lwg = wg - gg.wgStart;
  int bx = lwg & (gg.wgCols - 1);
  int by = lwg >> ((gg.wgCols == 2) ? 1 : 2);
  int N = gg.N, K = gg.K;

  __shared__ u16 As[128][40];
  __shared__ u16 Bs[128][40];
  int tid = threadIdx.x;
  int lane = tid & 63, wid = tid >> 6;
  int wr = (wid >> 1) * 64, wc = (wid & 1) * 64;
  int m16 = lane & 15, quad = lane >> 4;
  int rb = by * 128, cb = bx * 128;
  int srow = tid >> 2;
  int schunk = (tid & 3) * 8;

  f32x4 acc[4][4];
#pragma unroll
  for (int i = 0; i < 4; i++)
#pragma unroll
    for (int j = 0; j < 4; j++) acc[i][j] = (f32x4){0.f, 0.f, 0.f, 0.f};

  for (int k0 = 0; k0 < K; k0 += 32) {
    uint4 va0 = *(const uint4*)(gg.A + (size_t)(rb + srow) * K + k0 + schunk);
    uint4 va1 = *(const uint4*)(gg.A + (size_t)(rb + 64 + srow) * K + k0 + schunk);
    uint4 vb0 = *(const uint4*)(gg.WT + (size_t)(cb + srow) * K + k0 + schunk);
    uint4 vb1 = *(const uint4*)(gg.WT + (size_t)(cb + 64 + srow) * K + k0 + schunk);
    __syncthreads();
    *(uint4*)&As[srow][schunk] = va0;
    *(uint4*)&As[64 + srow][schunk] = va1;
    *(uint4*)&Bs[srow][schunk] = vb0;
    *(uint4*)&Bs[64 + srow][schunk] = vb1;
    __syncthreads();
    bf16x8 af[4], bfr[4];
#pragma unroll
    for (int i = 0; i < 4; i++)
      af[i] = *(const bf16x8*)&As[wr + i * 16 + m16][quad * 8];
#pragma unroll
    for (int j = 0; j < 4; j++)
      bfr[j] = *(const bf16x8*)&Bs[wc + j * 16 + m16][quad * 8];
#pragma unroll
    for (int i = 0; i < 4; i++)
#pragma unroll
      for (int j = 0; j < 4; j++)
        acc[i][j] = __builtin_amdgcn_mfma_f32_16x16x32_bf16(
            af[i], bfr[j], acc[i][j], 0, 0, 0);
  }

#pragma unroll
  for (int i = 0; i < 4; i++) {
#pragma unroll
    for (int j = 0; j < 4; j++) {
      int col = cb + wc + j * 16 + m16;
      float bv = (gg.epi >= 1) ? gg.bias[col] : 0.0f;
#pragma unroll
      for (int r = 0; r < 4; r++) {
        int row = rb + wr + i * 16 + quad * 4 + r;
        float v = acc[i][j][r] + bv;
        if (gg.epi == 2) v = fmaxf(v, 0.0f);
        size_t off;
        if (gg.mode == 0) {
          off = (size_t)row * N + col;
        } else if (gg.mode == 1) {          // q-pack: [row>>4][h][r16][d16]
          off = ((size_t)(row >> 4)) * 4096 + (size_t)(col >> 4) * 256 +
                (size_t)(row & 15) * 16 + (col & 15);
        } else {                            // k-pack: [b][h][c][d16]
          off = ((size_t)(row >> 7)) * 32768 + (size_t)(col >> 4) * 2048 +
                (size_t)(row & 127) * 16 + (col & 15);
        }
        gg.C[off] = f2bf(v);
      }
    }
  }
}

// ---------------------------------------------------------------------------
// Plain MFMA GEMM with f32 output (final ma-projection).
// ---------------------------------------------------------------------------
__global__ __launch_bounds__(256) void gemm_mfma_f32(
    const u16* __restrict__ A, const u16* __restrict__ WT,
    const float* __restrict__ bias, float* __restrict__ C,
    int M, int N, int K) {
  __shared__ u16 As[128][40];
  __shared__ u16 Bs[128][40];
  int tid = threadIdx.x;
  int lane = tid & 63, wid = tid >> 6;
  int wr = (wid >> 1) * 64, wc = (wid & 1) * 64;
  int m16 = lane & 15, quad = lane >> 4;
  int rb = blockIdx.y * 128, cb = blockIdx.x * 128;
  int srow = tid >> 2;
  int schunk = (tid & 3) * 8;
  f32x4 acc[4][4];
#pragma unroll
  for (int i = 0; i < 4; i++)
#pragma unroll
    for (int j = 0; j < 4; j++) acc[i][j] = (f32x4){0.f, 0.f, 0.f, 0.f};
  for (int k0 = 0; k0 < K; k0 += 32) {
    uint4 va0 = *(const uint4*)(A + (size_t)(rb + srow) * K + k0 + schunk);
    uint4 va1 = *(const uint4*)(A + (size_t)(rb + 64 + srow) * K + k0 + schunk);
    uint4 vb0 = *(const uint4*)(WT + (size_t)(cb + srow) * K + k0 + schunk);
    uint4 vb1 = *(const uint4*)(WT + (size_t)(cb + 64 + srow) * K + k0 + schunk);
    __syncthreads();
    *(uint4*)&As[srow][schunk] = va0;
    *(uint4*)&As[64 + srow][schunk] = va1;
    *(uint4*)&Bs[srow][schunk] = vb0;
    *(uint4*)&Bs[64 + srow][schunk] = vb1;
    __syncthreads();
    bf16x8 af[4], bfr[4];
#pragma unroll
    for (int i = 0; i < 4; i++)
      af[i] = *(const bf16x8*)&As[wr + i * 16 + m16][quad * 8];
#pragma unroll
    for (int j = 0; j < 4; j++)
      bfr[j] = *(const bf16x8*)&Bs[wc + j * 16 + m16][quad * 8];
#pragma unroll
    for (int i = 0; i < 4; i++)
#pragma unroll
      for (int j = 0; j < 4; j++)
        acc[i][j] = __builtin_amdgcn_mfma_f32_16x16x32_bf16(
            af[i], bfr[j], acc[i][j], 0, 0, 0);
  }
#pragma unroll
  for (int i = 0; i < 4; i++)
#pragma unroll
    for (int j = 0; j < 4; j++) {
      int col = cb + wc + j * 16 + m16;
      float bv = bias[col];
#pragma unroll
      for (int r = 0; r < 4; r++) {
        int row = rb + wr + i * 16 + quad * 4 + r;
        C[(size_t)row * N + col] = acc[i][j][r] + bv;
      }
    }
}

// ---------------------------------------------------------------------------
// Grouped fused MFMA attention: one block per 16-row tile, all 16 heads
// (wave w -> heads w*4..w*4+3 sequential). q/k in per-head-packed layout:
// frag loads are 512 B-contiguous per wave. Cost staged once as fp16.
// Mix-MLP in packed fp16 (__hfma2 + v_pk_max_f16); 0.25 folded into w10.
// ---------------------------------------------------------------------------
struct AG {
  const u16* q; const u16* k; const u16* vT; const float* cost; u16* ctx;
  const float* w1; const float* b1; const float* w2; const float* b2;
  int R, wgStart;
};
struct AGArgs { AG g[4]; };

#define CSTRIDE 134   // halves; <=2-way LDS banks on half2 reads

__global__ __launch_bounds__(256) void attn_grouped(AGArgs args) {
  int blk = blockIdx.x;
  int gi = 0;
#pragma unroll
  for (int i = 1; i < 4; i++)
    if (blk >= args.g[i].wgStart) gi = i;
  AG gg = args.g[gi];
  int local = blk - gg.wgStart;

  int t = threadIdx.x;
  int wave = t >> 6, lane = t & 63;
  int quad = lane >> 4, l16 = lane & 15;
  int m0 = local * 16;
  int b = m0 / gg.R;

  __shared__ __half costs_h[16 * CSTRIDE];
  __shared__ u16 pbuf[4][16 * 136];

  const float* cp = gg.cost + (size_t)m0 * 128;
  for (int i = t; i < 2048; i += 256)
    costs_h[(i >> 7) * CSTRIDE + (i & 127)] = __float2half(cp[i]);
  __syncthreads();

  const bf16x8 zerof = (bf16x8){0, 0, 0, 0, 0, 0, 0, 0};
  const f32x4 zacc = (f32x4){0.f, 0.f, 0.f, 0.f};
  const __half2 zh = __float2half2_rn(0.0f);
  u16* pb = pbuf[wave];
  const u16* qtile = gg.q + (size_t)local * 4096;      // [h][r16][d16]
  const u16* kb    = gg.k + (size_t)b * 32768;         // [h][c128][d16]

  for (int hh = 0; hh < 4; hh++) {
    int h = wave * 4 + hh;

    // wave-uniform mix weights (scalar loads); fold 0.25 into w10
    __half2 w10h[8], w11h[8], b1h[8], w2h[8];
#pragma unroll
    for (int s = 0; s < 8; s++) {
      w10h[s] = __float2half2_rn(gg.w1[h * 16 + s] * 0.25f);
      w11h[s] = __float2half2_rn(gg.w1[h * 16 + 8 + s]);
      b1h[s]  = __float2half2_rn(gg.b1[h * 8 + s]);
      w2h[s]  = __float2half2_rn(gg.w2[h * 8 + s]);
    }
    float wb2v = gg.b2[h];

    // QK^T (S^T layout): A = K rows, B = Q rows, zero-padded depth.
    // Packed layout: contiguous 512 B per (wave, head[, ct]).
    bf16x8 bq = zerof;
    if (quad < 2)
      bq = *(const bf16x8*)(qtile + (size_t)h * 256 + l16 * 16 + quad * 8);
    f32x4 st[8];
#pragma unroll
    for (int ct = 0; ct < 8; ct++) {
      bf16x8 ak = zerof;
      if (quad < 2)
        ak = *(const bf16x8*)(kb + (size_t)h * 2048 + (ct * 16 + l16) * 16 +
                              quad * 8);
      st[ct] = __builtin_amdgcn_mfma_f32_16x16x32_bf16(ak, bq, zacc, 0, 0, 0);
    }

    // mix-MLP, packed fp16 on (rg, rg+1) pairs
#pragma unroll
    for (int ct = 0; ct < 8; ct++) {
#pragma unroll
      for (int p = 0; p < 2; p++) {
        __half2 d2 = __float22half2_rn(
            make_float2(st[ct][p * 2], st[ct][p * 2 + 1]));
        __half2 c2 = *(const __half2*)&costs_h[l16 * CSTRIDE + ct * 16 +
                                               quad * 4 + p * 2];
        __half2 s2 = zh;
#pragma unroll
        for (int s = 0; s < 8; s++) {
          __half2 hm = __hfma2(d2, w10h[s], __hfma2(c2, w11h[s], b1h[s]));
          hm = h2max(hm, zh);
          s2 = __hfma2(hm, w2h[s], s2);
        }
        float2 sf = __half22float2(s2);
        st[ct][p * 2]     = sf.x + wb2v;
        st[ct][p * 2 + 1] = sf.y + wb2v;
      }
    }

    // softmax over c (32 in-reg + cross-quad shuffles)
    float mx = -1.0e30f;
#pragma unroll
    for (int ct = 0; ct < 8; ct++)
#pragma unroll
      for (int rg = 0; rg < 4; rg++) mx = fmaxf(mx, st[ct][rg]);
    mx = fmaxf(mx, __shfl_xor(mx, 16, 64));
    mx = fmaxf(mx, __shfl_xor(mx, 32, 64));
    float sum = 0.0f;
#pragma unroll
    for (int ct = 0; ct < 8; ct++)
#pragma unroll
      for (int rg = 0; rg < 4; rg++) {
        float e = __expf(st[ct][rg] - mx);
        st[ct][rg] = e;
        sum += e;
      }
    sum += __shfl_xor(sum, 16, 64);
    sum += __shfl_xor(sum, 32, 64);
    float inv = 1.0f / sum;

    // P -> per-wave LDS as packed bf16 pairs
#pragma unroll
    for (int ct = 0; ct < 8; ct++) {
#pragma unroll
      for (int p = 0; p < 2; p++) {
        __hip_bfloat162 pk = __float22bfloat162_rn(
            make_float2(st[ct][p * 2] * inv, st[ct][p * 2 + 1] * inv));
        *(unsigned int*)&pb[l16 * 136 + ct * 16 + quad * 4 + p * 2] =
            *(unsigned int*)&pk;
      }
    }

    // PV: B-frags from vT rows (contiguous 16B)
    f32x4 cacc = zacc;
#pragma unroll
    for (int ks = 0; ks < 4; ks++) {
      bf16x8 ap = *(const bf16x8*)&pb[l16 * 136 + ks * 32 + quad * 8];
      bf16x8 bv = *(const bf16x8*)(gg.vT + (size_t)b * 32768 +
                                   (size_t)(h * 16 + l16) * 128 + ks * 32 +
                                   quad * 8);
      cacc = __builtin_amdgcn_mfma_f32_16x16x32_bf16(ap, bv, cacc, 0, 0, 0);
    }

#pragma unroll
    for (int rg = 0; rg < 4; rg++)
      gg.ctx[(size_t)(m0 + quad * 4 + rg) * 256 + h * 16 + l16] =
          f2bf(cacc[rg]);
  }
}

// ---------------------------------------------------------------------------
// Grouped LN1 / LN2.
// ---------------------------------------------------------------------------
struct LN1Args {
  const float* r0; const float* r1; const float* r2; const float* r3;
  int s1, s2, s3;
};
__global__ __launch_bounds__(256) void ln1_grouped(
    LN1Args a, const u16* __restrict__ x, u16* __restrict__ out) {
  int row = blockIdx.x, t = threadIdx.x;
  const float* resid;
  int local;
  if (row < a.s1)      { resid = a.r0; local = row; }
  else if (row < a.s2) { resid = a.r1; local = row - a.s1; }
  else if (row < a.s3) { resid = a.r2; local = row - a.s2; }
  else                 { resid = a.r3; local = row - a.s3; }
  float vv = resid[(size_t)local * 256 + t] + bf2f(x[(size_t)row * 256 + t]);
  __shared__ float red[256];
  red[t] = vv;
  __syncthreads();
  for (int s = 128; s > 0; s >>= 1) {
    if (t < s) red[t] += red[t + s];
    __syncthreads();
  }
  float mean = red[0] * (1.0f / 256.0f);
  __syncthreads();
  float d = vv - mean;
  red[t] = d * d;
  __syncthreads();
  for (int s = 128; s > 0; s >>= 1) {
    if (t < s) red[t] += red[t + s];
    __syncthreads();
  }
  float var = red[0] * (1.0f / 256.0f);
  out[(size_t)row * 256 + t] = f2bf(d * rsqrtf(var + 1e-5f));
}

struct LN2Args {
  float* f0; float* f1; u16* b2; u16* b3;
  int s1, s2, s3;
};
__global__ __launch_bounds__(256) void ln2_grouped(
    LN2Args a, const u16* __restrict__ resid, const u16* __restrict__ x) {
  int row = blockIdx.x, t = threadIdx.x;
  float vv = bf2f(resid[(size_t)row * 256 + t]) + bf2f(x[(size_t)row * 256 + t]);
  __shared__ float red[256];
  red[t] = vv;
  __syncthreads();
  for (int s = 128; s > 0; s >>= 1) {
    if (t < s) red[t] += red[t + s];
    __syncthreads();
  }
  float mean = red[0] * (1.0f / 256.0f);
  __syncthreads();
  float d = vv - mean;
  red[t] = d * d;
  __syncthreads();
  for (int s = 128; s > 0; s >>= 1) {
    if (t < s) red[t] += red[t + s];
    __syncthreads();
  }
  float var = red[0] * (1.0f / 256.0f);
  float y = d * rsqrtf(var + 1e-5f);
  if (row < a.s1)
    a.f0[(size_t)row * 256 + t] = y;
  else if (row < a.s2)
    a.f1[(size_t)(row - a.s1) * 256 + t] = y;
  else if (row < a.s3)
    a.b2[(size_t)(row - a.s2) * 512 + t] = f2bf(y);
  else
    a.b3[(size_t)(row - a.s3) * 512 + 256 + t] = f2bf(y);
}

// ---------------------------------------------------------------------------
extern "C" void kernel_launch(void* const* d_in, const int* in_sizes, int n_in,
                              void* d_out, int out_size, void* d_ws, size_t ws_size,
                              hipStream_t stream) {
  const float* ope   = (const float*)d_in[0];
  const float* ma    = (const float*)d_in[1];
  const float* veh   = (const float*)d_in[2];
  const float* proc  = (const float*)d_in[3];
  const float* trans = (const float*)d_in[5];
  const float* mv    = (const float*)d_in[6];
  const int* mask_dyn = (const int*)d_in[7];
  const int* mask_ma  = (const int*)d_in[8];
  const float* Wq = (const float*)d_in[9];
  const float* Wk = (const float*)d_in[10];
  const float* Wv = (const float*)d_in[11];
  const float* Wo = (const float*)d_in[12];
  const float* mixW1 = (const float*)d_in[13];
  const float* mixb1 = (const float*)d_in[14];
  const float* mixW2 = (const float*)d_in[15];
  const float* mixb2 = (const float*)d_in[16];
  const float* ffW1 = (const float*)d_in[17];
  const float* ffb1 = (const float*)d_in[18];
  const float* ffW2 = (const float*)d_in[19];
  const float* ffb2 = (const float*)d_in[20];
  const float* maprojW = (const float*)d_in[21];
  const float* maprojb = (const float*)d_in[22];
  float* out = (float*)d_out;
  char* ws = (char*)d_ws;

  const int OFF[4] = {0, 8192, 9216, 11264};
  const int MS4[4] = {8192, 1024, 2048, 2048};
  const int TOT = 13312;

  const size_t MB = 1 << 20;
  float* A_proc  = (float*)(ws + 0);
  float* A_offb  = (float*)(ws + 4 * MB);
  float* A_pcing = (float*)(ws + 4 * MB + MB / 2);
  float* A_on    = (float*)(ws + 5 * MB + MB / 2);
  u16* ope_bf  = (u16*)(ws + 6 * MB + MB / 2);
  u16* ma_bf   = (u16*)(ws + 10 * MB + MB / 2);
  u16* veh_bf  = (u16*)(ws + 11 * MB + MB / 2);
  u16* WqT     = (u16*)(ws + 12 * MB);
  u16* WkT     = (u16*)(ws + 12 * MB + MB / 2);
  u16* WvT     = (u16*)(ws + 13 * MB);
  u16* WoT     = (u16*)(ws + 13 * MB + MB / 2);
  u16* ffW1T   = (u16*)(ws + 14 * MB);
  u16* ffW2T   = (u16*)(ws + 15 * MB);
  u16* maprojT = (u16*)(ws + 16 * MB);
  u16* q_all   = (u16*)(ws + 16 * MB + MB / 2);   // packed [tile][h][r][d]
  u16* k_all   = (u16*)(ws + 23 * MB);            // packed [g][b][h][c][d]
  u16* v_all   = (u16*)(ws + 27 * MB);
  u16* vT_all  = (u16*)(ws + 31 * MB);
  u16* ctx_all = (u16*)(ws + 35 * MB);
  u16* t1_all  = (u16*)(ws + 41 * MB + MB / 2);
  u16* out1_all= (u16*)(ws + 48 * MB);
  u16* ffh_all = (u16*)(ws + 54 * MB + MB / 2);
  u16* maCat   = (u16*)(ws + 67 * MB + MB / 2);

  // --- prep (converts + adjacency), 1 dispatch ---
  {
    PrepArgs pa = {ope, ma, veh, ope_bf, ma_bf, veh_bf,
                   proc, mask_dyn, A_proc, mv, A_offb,
                   trans, mask_ma, A_on, A_pcing};
    prep_grouped<<<6944, 256, 0, stream>>>(pa);
  }

  // --- weight transposes, 1 dispatch ---
  {
    TrArgs ta = {Wq, Wk, Wv, Wo, ffW1, ffW2, maprojW,
                 WqT, WkT, WvT, WoT, ffW1T, ffW2T, maprojT};
    transpose_all<<<2176, 256, 0, stream>>>(ta);
  }

  const size_t MA_OUT  = (size_t)NBATCH * NOPE * EDIM;
  const size_t VEH_OUT = MA_OUT + (size_t)NBATCH * NMA * EDIM;

  const u16* rowbf[4] = {ope_bf, veh_bf, ma_bf, ma_bf};
  const float* costp[4] = {A_proc, A_offb, A_pcing, A_on};

  // --- grouped GEMM #1: q(x4, q-pack) + k(x4, k-pack) + v(x4, row-major) ---
  {
    GGArgs ga; ga.n = 12;
    int wg = 0;
    for (int i = 0; i < 4; i++) {
      ga.g[i] = {rowbf[i], WqT + (size_t)i * 65536, nullptr,
                 q_all + (size_t)OFF[i] * 256, MS4[i], 256, 256, 0, wg, 2, 1};
      wg += (MS4[i] / 128) * 2;
    }
    for (int i = 0; i < 4; i++) {
      ga.g[4 + i] = {ma_bf, WkT + (size_t)i * 65536, nullptr,
                     k_all + (size_t)i * 524288, 2048, 256, 256, 0, wg, 2, 2};
      wg += 32;
    }
    for (int i = 0; i < 4; i++) {
      ga.g[8 + i] = {ma_bf, WvT + (size_t)i * 65536, nullptr,
                     v_all + (size_t)i * 524288, 2048, 256, 256, 0, wg, 2, 0};
      wg += 32;
    }
    gemm_grouped<<<wg, 256, 0, stream>>>(ga);
  }

  transpose_v<<<dim3(8, 4, 64), 256, 0, stream>>>(v_all, vT_all);

  // --- grouped attention: 832 blocks (16-row tiles) ---
  {
    AGArgs aa;
    int wg = 0;
    const int R4[4] = {NOPE, NVEH, NMA, NMA};
    for (int i = 0; i < 4; i++) {
      aa.g[i] = {q_all + (size_t)OFF[i] * 256, k_all + (size_t)i * 524288,
                 vT_all + (size_t)i * 524288, costp[i],
                 ctx_all + (size_t)OFF[i] * 256,
                 mixW1 + (size_t)i * 256, mixb1 + (size_t)i * 128,
                 mixW2 + (size_t)i * 128, mixb2 + (size_t)i * 16,
                 R4[i], wg};
      wg += MS4[i] / 16;
    }
    attn_grouped<<<wg, 256, 0, stream>>>(aa);
  }

  // --- Wo ---
  {
    GGArgs ga; ga.n = 4;
    int wg = 0;
    for (int i = 0; i < 4; i++) {
      ga.g[i] = {ctx_all + (size_t)OFF[i] * 256, WoT + (size_t)i * 65536,
                 nullptr, t1_all + (size_t)OFF[i] * 256,
                 MS4[i], 256, 256, 0, wg, 2, 0};
      wg += (MS4[i] / 128) * 2;
    }
    gemm_grouped<<<wg, 256, 0, stream>>>(ga);
  }

  {
    LN1Args la = {ope, veh, ma, ma, 8192, 9216, 11264};
    ln1_grouped<<<TOT, 256, 0, stream>>>(la, t1_all, out1_all);
  }

  // --- FF1 (bias+relu) ---
  {
    GGArgs ga; ga.n = 4;
    int wg = 0;
    for (int i = 0; i < 4; i++) {
      ga.g[i] = {out1_all + (size_t)OFF[i] * 256, ffW1T + (size_t)i * 131072,
                 ffb1 + (size_t)i * 512, ffh_all + (size_t)OFF[i] * 512,
                 MS4[i], 512, 256, 2, wg, 4, 0};
      wg += (MS4[i] / 128) * 4;
    }
    gemm_grouped<<<wg, 256, 0, stream>>>(ga);
  }

  // --- FF2 (bias) ---
  {
    GGArgs ga; ga.n = 4;
    int wg = 0;
    for (int i = 0; i < 4; i++) {
      ga.g[i] = {ffh_all + (size_t)OFF[i] * 512, ffW2T + (size_t)i * 131072,
                 ffb2 + (size_t)i * 256, t1_all + (size_t)OFF[i] * 256,
                 MS4[i], 256, 512, 1, wg, 2, 0};
      wg += (MS4[i] / 128) * 2;
    }
    gemm_grouped<<<wg, 256, 0, stream>>>(ga);
  }

  {
    LN2Args la = {out, out + VEH_OUT, maCat, maCat, 8192, 9216, 11264};
    ln2_grouped<<<TOT, 256, 0, stream>>>(la, out1_all, t1_all);
  }

  gemm_mfma_f32<<<dim3(2, 16), 256, 0, stream>>>(maCat, maprojT, maprojb,
      out + MA_OUT, 2048, 256, 512);
}

// Round 12
// 288.029 us; speedup vs baseline: 1.0542x; 1.0542x over previous
//
#include <hip/hip_runtime.h>
#include <hip/hip_fp16.h>
#include <hip/hip_bf16.h>

// ---------------------------------------------------------------------------
// EncoderLayer (MatNet mixed-score MHA) for MI355X — R12.
// R12 = R11 + (a) prep split: wide atomic min/max partials + streaming
// normalize (R11's prep had 16-block tail sections -> 46 us at 3% VALU);
// (b) attn XCD swizzle: tile order remapped so XCD x serves batches
// {2x,2x+1} -> k/vT L2-resident per XCD.
// Inputs f32, masks int32, d_out f32. Row-space: ope[0,8192) veh[8192,9216)
// ma1[9216,11264) ma2[11264,13312).
// ---------------------------------------------------------------------------

typedef unsigned short u16;
typedef __attribute__((ext_vector_type(8))) short bf16x8;
typedef __attribute__((ext_vector_type(4))) float f32x4;
struct us4 { u16 x, y, z, w; };

__device__ __forceinline__ float bf2f(u16 u) {
  return __uint_as_float(((unsigned int)u) << 16);
}
__device__ __forceinline__ u16 f2bf(float f) {
  unsigned int x = __float_as_uint(f);
  x += 0x7FFFu + ((x >> 16) & 1u);
  return (u16)(x >> 16);
}
// packed fp16 max (ROCm 7.2 lacks the __half2 __hmax2 overload on gfx950)
__device__ __forceinline__ __half2 h2max(__half2 a, __half2 b) {
  unsigned au = *(unsigned*)&a, bu = *(unsigned*)&b, ru;
  asm("v_pk_max_f16 %0, %1, %2" : "=v"(ru) : "v"(au), "v"(bu));
  return *(__half2*)&ru;
}

#define NBATCH 16
#define NOPE   512
#define NMA    128
#define NVEH   64
#define EDIM   256

// ---------------------------------------------------------------------------
// prep_a: [0,2816) f32->bf16 converts; [2816,6912) aproc (2 rows/blk);
// [6912,6976) aoff min/max partials (4 blk/b); [6976,7104) aon min/max
// partials (8 blk/b). mm layout: mins[32] (aoff b, aon 16+b), maxs[32].
// Values are >=0 so float bits compare monotonically as unsigned.
// ---------------------------------------------------------------------------
struct PrepArgs {
  const float* ope; const float* ma; const float* veh;
  u16* ope_bf; u16* ma_bf; u16* veh_bf;
  const float* proc; const int* mask_dyn; float* A_proc;
  const float* mv; const float* trans; const int* mask_ma;
  unsigned int* mm;   // [64]: mins[32], maxs[32]
};
__global__ __launch_bounds__(256) void prep_a(PrepArgs a) {
  int blk = blockIdx.x, t = threadIdx.x;
  if (blk < 2816) {
    int i = blk * 256 + t;
    const float* s; u16* d; int j;
    if (i < 524288)      { s = a.ope; d = a.ope_bf; j = i; }
    else if (i < 655360) { s = a.ma;  d = a.ma_bf;  j = i - 524288; }
    else                 { s = a.veh; d = a.veh_bf; j = i - 655360; }
    float4 v = ((const float4*)s)[j];
    us4 o = { f2bf(v.x), f2bf(v.y), f2bf(v.z), f2bf(v.w) };
    ((us4*)d)[j] = o;
    return;
  }
  if (blk < 6912) {
    int local = blk - 2816;
    int row = local * 2 + (t >> 7);
    int lane = t & 127;
    size_t idx = (size_t)row * NMA + lane;
    float av = a.mask_dyn[idx] ? a.proc[idx] : 0.0f;
    float cand = (av != 0.0f) ? av : 1.0e30f;
    __shared__ float red[256];
    red[t] = cand;
    __syncthreads();
    for (int s = 64; s > 0; s >>= 1) {
      if (lane < s) red[t] = fminf(red[t], red[t + s]);
      __syncthreads();
    }
    float mn = red[t & 128];
    a.A_proc[idx] = (av != 0.0f && av == mn) ? 1.0f : 0.0f;
    return;
  }
  __shared__ float smn[256], smx[256];
  float mn = 1.0e30f, mx = -1.0e30f;
  int mmIdx;
  if (blk < 6976) {
    int local = blk - 6912;
    int b = local >> 2, chunk = local & 3;
    const float* xb = a.mv + (size_t)b * 8192 + chunk * 2048;
#pragma unroll
    for (int r = 0; r < 8; r++) {
      float v = xb[r * 256 + t];
      mn = fminf(mn, v);
      mx = fmaxf(mx, v);
    }
    mmIdx = b;
  } else {
    int local = blk - 6976;
    int b = local >> 3, chunk = local & 7;
    __shared__ unsigned char mrow[NMA];
    if (t < NMA) mrow[t] = (unsigned char)(a.mask_ma[(size_t)b * NMA + t] != 0);
    __syncthreads();
    const float* tb = a.trans + (size_t)b * 16384 + chunk * 2048;
    int rbase = chunk * 16;   // 2048 elems = rows rbase..rbase+15
#pragma unroll
    for (int r = 0; r < 8; r++) {
      int off = r * 256 + t;
      int row = rbase + (off >> 7), col = off & 127;
      bool m2 = mrow[row] && mrow[col];
      float tt = m2 ? tb[off] : 101.0f;
      mn = fminf(mn, tt);
      mx = fmaxf(mx, tt);
    }
    mmIdx = 16 + b;
  }
  smn[t] = mn; smx[t] = mx;
  __syncthreads();
  for (int s = 128; s > 0; s >>= 1) {
    if (t < s) {
      smn[t] = fminf(smn[t], smn[t + s]);
      smx[t] = fmaxf(smx[t], smx[t + s]);
    }
    __syncthreads();
  }
  if (t == 0) {
    atomicMin(&a.mm[mmIdx], __float_as_uint(smn[0]));
    atomicMax(&a.mm[32 + mmIdx], __float_as_uint(smx[0]));
  }
}

// ---------------------------------------------------------------------------
// prep_b: [0,512) aoff normalize; [512,1536) aon normalize + A_pcing.
// ---------------------------------------------------------------------------
__global__ __launch_bounds__(256) void prep_b(
    const float* __restrict__ mv, const float* __restrict__ trans,
    const int* __restrict__ mask_ma, const unsigned int* __restrict__ mm,
    float* __restrict__ A_offb, float* __restrict__ a_on,
    float* __restrict__ a_pcing) {
  int blk = blockIdx.x, t = threadIdx.x;
  if (blk < 512) {
    int b = blk >> 5, off = (blk & 31) * 256 + t;
    float lo = __uint_as_float(mm[b]);
    float inv = 1.0f / (__uint_as_float(mm[32 + b]) - lo);
    size_t idx = (size_t)b * 8192 + off;
    A_offb[idx] = 1.0f - (mv[idx] - lo) * inv;
    return;
  }
  int local = blk - 512;
  int b = local >> 6, off = (local & 63) * 256 + t;
  int row = off >> 7, col = off & 127;
  bool m2 = (mask_ma[(size_t)b * NMA + row] != 0) &&
            (mask_ma[(size_t)b * NMA + col] != 0);
  size_t idx = (size_t)b * 16384 + off;
  float tt = m2 ? trans[idx] : 101.0f;
  float lo = __uint_as_float(mm[16 + b]);
  float inv = 1.0f / (__uint_as_float(mm[48 + b]) - lo);
  a_on[idx] = 1.0f - (tt - lo) * inv;
  a_pcing[idx] = m2 ? 0.0f : 1.0f;
}

// ---------------------------------------------------------------------------
// Merged weight transposes: f32 [Kd][Nd] -> bf16 [Nd][Kd], 32x32 tiles.
// ---------------------------------------------------------------------------
struct TrArgs {
  const float* Wq; const float* Wk; const float* Wv; const float* Wo;
  const float* ffW1; const float* ffW2; const float* maproj;
  u16* WqT; u16* WkT; u16* WvT; u16* WoT; u16* ffW1T; u16* ffW2T; u16* maprojT;
};
__global__ __launch_bounds__(256) void transpose_all(TrArgs a) {
  int blk = blockIdx.x;
  const float* src; u16* dst; int Kd, Nd, tile;
  if (blk < 1024) {
    int w = blk >> 8, i = (blk >> 6) & 3; tile = blk & 63;
    const float* sw = (w == 0 ? a.Wq : w == 1 ? a.Wk : w == 2 ? a.Wv : a.Wo);
    u16* dw = (w == 0 ? a.WqT : w == 1 ? a.WkT : w == 2 ? a.WvT : a.WoT);
    src = sw + (size_t)i * 65536; dst = dw + (size_t)i * 65536;
    Kd = 256; Nd = 256;
  } else if (blk < 1536) {
    int z = (blk - 1024) >> 7; tile = (blk - 1024) & 127;
    src = a.ffW1 + (size_t)z * 131072; dst = a.ffW1T + (size_t)z * 131072;
    Kd = 256; Nd = 512;
  } else {
    int z = (blk - 1536) >> 7; tile = (blk - 1536) & 127;
    if (z < 4) { src = a.ffW2 + (size_t)z * 131072; dst = a.ffW2T + (size_t)z * 131072; }
    else       { src = a.maproj; dst = a.maprojT; }
    Kd = 512; Nd = 256;
  }
  int nx = Nd >> 5;
  int k0 = (tile / nx) * 32, n0 = (tile % nx) * 32;
  __shared__ float tl[32][33];
  int tx = threadIdx.x & 31, ty = threadIdx.x >> 5;
#pragma unroll
  for (int r = 0; r < 4; r++)
    tl[ty + r * 8][tx] = src[(size_t)(k0 + ty + r * 8) * Nd + n0 + tx];
  __syncthreads();
#pragma unroll
  for (int r = 0; r < 4; r++)
    dst[(size_t)(n0 + ty + r * 8) * Kd + k0 + tx] = f2bf(tl[tx][ty + r * 8]);
}

// ---------------------------------------------------------------------------
// v_all [4][16 b][128 c][256 d] -> vT_all [4][16 b][256 d][128 c], bf16.
// ---------------------------------------------------------------------------
__global__ __launch_bounds__(256) void transpose_v(
    const u16* __restrict__ src, u16* __restrict__ dst) {
  int g = blockIdx.z >> 4, b = blockIdx.z & 15;
  int d0 = blockIdx.x * 32, c0 = blockIdx.y * 32;
  __shared__ u16 tile[32][33];
  int tx = threadIdx.x & 31, ty = threadIdx.x >> 5;
  const u16* s = src + ((size_t)g * 16 + b) * 32768;
  u16* d = dst + ((size_t)g * 16 + b) * 32768;
#pragma unroll
  for (int r = 0; r < 4; r++)
    tile[ty + r * 8][tx] = s[(size_t)(c0 + ty + r * 8) * 256 + d0 + tx];
  __syncthreads();
#pragma unroll
  for (int r = 0; r < 4; r++)
    d[(size_t)(d0 + ty + r * 8) * 128 + c0 + tx] = tile[tx][ty + r * 8];
}

// ---------------------------------------------------------------------------
// Grouped MFMA GEMM. mode: 0 = row-major C, 1 = q-pack C[tile][h][r][d16],
// 2 = k-pack C[b][h][c][d16].
// ---------------------------------------------------------------------------
struct GG {
  const u16* A; const u16* WT; const float* bias; u16* C;
  int M, N, K, epi, wgStart, wgCols, mode;
};
struct GGArgs { GG g[12]; int n; };

__global__ __launch_bounds__(256) void gemm_grouped(GGArgs args) {
  int wg = blockIdx.x;
  int gi = 0;
  for (int i = 1; i < args.n; i++)
    if (wg >= args.g[i].wgStart) gi = i;
  GG gg = args.g[gi];
  int lwg = wg - gg.wgStart;
  int bx = lwg & (gg.wgCols - 1);
  int by = lwg >> ((gg.wgCols == 2) ? 1 : 2);
  int N = gg.N, K = gg.K;

  __shared__ u16 As[128][40];
  __shared__ u16 Bs[128][40];
  int tid = threadIdx.x;
  int lane = tid & 63, wid = tid >> 6;
  int wr = (wid >> 1) * 64, wc = (wid & 1) * 64;
  int m16 = lane & 15, quad = lane >> 4;
  int rb = by * 128, cb = bx * 128;
  int srow = tid >> 2;
  int schunk = (tid & 3) * 8;

  f32x4 acc[4][4];
#pragma unroll
  for (int i = 0; i < 4; i++)
#pragma unroll
    for (int j = 0; j < 4; j++) acc[i][j] = (f32x4){0.f, 0.f, 0.f, 0.f};

  for (int k0 = 0; k0 < K; k0 += 32) {
    uint4 va0 = *(const uint4*)(gg.A + (size_t)(rb + srow) * K + k0 + schunk);
    uint4 va1 = *(const uint4*)(gg.A + (size_t)(rb + 64 + srow) * K + k0 + schunk);
    uint4 vb0 = *(const uint4*)(gg.WT + (size_t)(cb + srow) * K + k0 + schunk);
    uint4 vb1 = *(const uint4*)(gg.WT + (size_t)(cb + 64 + srow) * K + k0 + schunk);
    __syncthreads();
    *(uint4*)&As[srow][schunk] = va0;
    *(uint4*)&As[64 + srow][schunk] = va1;
    *(uint4*)&Bs[srow][schunk] = vb0;
    *(uint4*)&Bs[64 + srow][schunk] = vb1;
    __syncthreads();
    bf16x8 af[4], bfr[4];
#pragma unroll
    for (int i = 0; i < 4; i++)
      af[i] = *(const bf16x8*)&As[wr + i * 16 + m16][quad * 8];
#pragma unroll
    for (int j = 0; j < 4; j++)
      bfr[j] = *(const bf16x8*)&Bs[wc + j * 16 + m16][quad * 8];
#pragma unroll
    for (int i = 0; i < 4; i++)
#pragma unroll
      for (int j = 0; j < 4; j++)
        acc[i][j] = __builtin_amdgcn_mfma_f32_16x16x32_bf16(
            af[i], bfr[j], acc[i][j], 0, 0, 0);
  }

#pragma unroll
  for (int i = 0; i < 4; i++) {
#pragma unroll
    for (int j = 0; j < 4; j++) {
      int col = cb + wc + j * 16 + m16;
      float bv = (gg.epi >= 1) ? gg.bias[col] : 0.0f;
#pragma unroll
      for (int r = 0; r < 4; r++) {
        int row = rb + wr + i * 16 + quad * 4 + r;
        float v = acc[i][j][r] + bv;
        if (gg.epi == 2) v = fmaxf(v, 0.0f);
        size_t off;
        if (gg.mode == 0) {
          off = (size_t)row * N + col;
        } else if (gg.mode == 1) {          // q-pack: [row>>4][h][r16][d16]
          off = ((size_t)(row >> 4)) * 4096 + (size_t)(col >> 4) * 256 +
                (size_t)(row & 15) * 16 + (col & 15);
        } else {                            // k-pack: [b][h][c][d16]
          off = ((size_t)(row >> 7)) * 32768 + (size_t)(col >> 4) * 2048 +
                (size_t)(row & 127) * 16 + (col & 15);
        }
        gg.C[off] = f2bf(v);
      }
    }
  }
}

// ---------------------------------------------------------------------------
// Plain MFMA GEMM with f32 output (final ma-projection).
// ---------------------------------------------------------------------------
__global__ __launch_bounds__(256) void gemm_mfma_f32(
    const u16* __restrict__ A, const u16* __restrict__ WT,
    const float* __restrict__ bias, float* __restrict__ C,
    int M, int N, int K) {
  __shared__ u16 As[128][40];
  __shared__ u16 Bs[128][40];
  int tid = threadIdx.x;
  int lane = tid & 63, wid = tid >> 6;
  int wr = (wid >> 1) * 64, wc = (wid & 1) * 64;
  int m16 = lane & 15, quad = lane >> 4;
  int rb = blockIdx.y * 128, cb = blockIdx.x * 128;
  int srow = tid >> 2;
  int schunk = (tid & 3) * 8;
  f32x4 acc[4][4];
#pragma unroll
  for (int i = 0; i < 4; i++)
#pragma unroll
    for (int j = 0; j < 4; j++) acc[i][j] = (f32x4){0.f, 0.f, 0.f, 0.f};
  for (int k0 = 0; k0 < K; k0 += 32) {
    uint4 va0 = *(const uint4*)(A + (size_t)(rb + srow) * K + k0 + schunk);
    uint4 va1 = *(const uint4*)(A + (size_t)(rb + 64 + srow) * K + k0 + schunk);
    uint4 vb0 = *(const uint4*)(WT + (size_t)(cb + srow) * K + k0 + schunk);
    uint4 vb1 = *(const uint4*)(WT + (size_t)(cb + 64 + srow) * K + k0 + schunk);
    __syncthreads();
    *(uint4*)&As[srow][schunk] = va0;
    *(uint4*)&As[64 + srow][schunk] = va1;
    *(uint4*)&Bs[srow][schunk] = vb0;
    *(uint4*)&Bs[64 + srow][schunk] = vb1;
    __syncthreads();
    bf16x8 af[4], bfr[4];
#pragma unroll
    for (int i = 0; i < 4; i++)
      af[i] = *(const bf16x8*)&As[wr + i * 16 + m16][quad * 8];
#pragma unroll
    for (int j = 0; j < 4; j++)
      bfr[j] = *(const bf16x8*)&Bs[wc + j * 16 + m16][quad * 8];
#pragma unroll
    for (int i = 0; i < 4; i++)
#pragma unroll
      for (int j = 0; j < 4; j++)
        acc[i][j] = __builtin_amdgcn_mfma_f32_16x16x32_bf16(
            af[i], bfr[j], acc[i][j], 0, 0, 0);
  }
#pragma unroll
  for (int i = 0; i < 4; i++)
#pragma unroll
    for (int j = 0; j < 4; j++) {
      int col = cb + wc + j * 16 + m16;
      float bv = bias[col];
#pragma unroll
      for (int r = 0; r < 4; r++) {
        int row = rb + wr + i * 16 + quad * 4 + r;
        C[(size_t)row * N + col] = acc[i][j][r] + bv;
      }
    }
}

// ---------------------------------------------------------------------------
// Grouped fused MFMA attention with XCD swizzle: local -> (b,tile) such that
// XCD x (= blockIdx%8) serves batches {2x,2x+1} (k/vT L2-resident per XCD).
// One block per 16-row tile, all 16 heads (4/wave). q/k per-head-packed.
// ---------------------------------------------------------------------------
struct AG {
  const u16* q; const u16* k; const u16* vT; const float* cost; u16* ctx;
  const float* w1; const float* b1; const float* w2; const float* b2;
  int R, wgStart;
};
struct AGArgs { AG g[4]; };

#define CSTRIDE 134   // halves; <=2-way LDS banks on half2 reads

__global__ __launch_bounds__(256) void attn_grouped(AGArgs args) {
  int blk = blockIdx.x;
  int gi = 0;
#pragma unroll
  for (int i = 1; i < 4; i++)
    if (blk >= args.g[i].wgStart) gi = i;
  AG gg = args.g[gi];
  int local = blk - gg.wgStart;

  int t = threadIdx.x;
  int wave = t >> 6, lane = t & 63;
  int quad = lane >> 4, l16 = lane & 15;
  // XCD swizzle: j = local&15 -> b; tile = local>>4. wgStarts are %8==0.
  int j = local & 15;
  int b = (j & 7) * 2 + (j >> 3);
  int tile = local >> 4;
  int m0 = b * gg.R + tile * 16;

  __shared__ __half costs_h[16 * CSTRIDE];
  __shared__ u16 pbuf[4][16 * 136];

  const float* cp = gg.cost + (size_t)m0 * 128;
  for (int i = t; i < 2048; i += 256)
    costs_h[(i >> 7) * CSTRIDE + (i & 127)] = __float2half(cp[i]);
  __syncthreads();

  const bf16x8 zerof = (bf16x8){0, 0, 0, 0, 0, 0, 0, 0};
  const f32x4 zacc = (f32x4){0.f, 0.f, 0.f, 0.f};
  const __half2 zh = __float2half2_rn(0.0f);
  u16* pb = pbuf[wave];
  const u16* qtile = gg.q + ((size_t)(m0 >> 4)) * 4096;   // [h][r16][d16]
  const u16* kb    = gg.k + (size_t)b * 32768;            // [h][c128][d16]

  for (int hh = 0; hh < 4; hh++) {
    int h = wave * 4 + hh;

    __half2 w10h[8], w11h[8], b1h[8], w2h[8];
#pragma unroll
    for (int s = 0; s < 8; s++) {
      w10h[s] = __float2half2_rn(gg.w1[h * 16 + s] * 0.25f);
      w11h[s] = __float2half2_rn(gg.w1[h * 16 + 8 + s]);
      b1h[s]  = __float2half2_rn(gg.b1[h * 8 + s]);
      w2h[s]  = __float2half2_rn(gg.w2[h * 8 + s]);
    }
    float wb2v = gg.b2[h];

    bf16x8 bq = zerof;
    if (quad < 2)
      bq = *(const bf16x8*)(qtile + (size_t)h * 256 + l16 * 16 + quad * 8);
    f32x4 st[8];
#pragma unroll
    for (int ct = 0; ct < 8; ct++) {
      bf16x8 ak = zerof;
      if (quad < 2)
        ak = *(const bf16x8*)(kb + (size_t)h * 2048 + (ct * 16 + l16) * 16 +
                              quad * 8);
      st[ct] = __builtin_amdgcn_mfma_f32_16x16x32_bf16(ak, bq, zacc, 0, 0, 0);
    }

#pragma unroll
    for (int ct = 0; ct < 8; ct++) {
#pragma unroll
      for (int p = 0; p < 2; p++) {
        __half2 d2 = __float22half2_rn(
            make_float2(st[ct][p * 2], st[ct][p * 2 + 1]));
        __half2 c2 = *(const __half2*)&costs_h[l16 * CSTRIDE + ct * 16 +
                                               quad * 4 + p * 2];
        __half2 s2 = zh;
#pragma unroll
        for (int s = 0; s < 8; s++) {
          __half2 hm = __hfma2(d2, w10h[s], __hfma2(c2, w11h[s], b1h[s]));
          hm = h2max(hm, zh);
          s2 = __hfma2(hm, w2h[s], s2);
        }
        float2 sf = __half22float2(s2);
        st[ct][p * 2]     = sf.x + wb2v;
        st[ct][p * 2 + 1] = sf.y + wb2v;
      }
    }

    float mx = -1.0e30f;
#pragma unroll
    for (int ct = 0; ct < 8; ct++)
#pragma unroll
      for (int rg = 0; rg < 4; rg++) mx = fmaxf(mx, st[ct][rg]);
    mx = fmaxf(mx, __shfl_xor(mx, 16, 64));
    mx = fmaxf(mx, __shfl_xor(mx, 32, 64));
    float sum = 0.0f;
#pragma unroll
    for (int ct = 0; ct < 8; ct++)
#pragma unroll
      for (int rg = 0; rg < 4; rg++) {
        float e = __expf(st[ct][rg] - mx);
        st[ct][rg] = e;
        sum += e;
      }
    sum += __shfl_xor(sum, 16, 64);
    sum += __shfl_xor(sum, 32, 64);
    float inv = 1.0f / sum;

#pragma unroll
    for (int ct = 0; ct < 8; ct++) {
#pragma unroll
      for (int p = 0; p < 2; p++) {
        __hip_bfloat162 pk = __float22bfloat162_rn(
            make_float2(st[ct][p * 2] * inv, st[ct][p * 2 + 1] * inv));
        *(unsigned int*)&pb[l16 * 136 + ct * 16 + quad * 4 + p * 2] =
            *(unsigned int*)&pk;
      }
    }

    f32x4 cacc = zacc;
#pragma unroll
    for (int ks = 0; ks < 4; ks++) {
      bf16x8 ap = *(const bf16x8*)&pb[l16 * 136 + ks * 32 + quad * 8];
      bf16x8 bv = *(const bf16x8*)(gg.vT + (size_t)b * 32768 +
                                   (size_t)(h * 16 + l16) * 128 + ks * 32 +
                                   quad * 8);
      cacc = __builtin_amdgcn_mfma_f32_16x16x32_bf16(ap, bv, cacc, 0, 0, 0);
    }

#pragma unroll
    for (int rg = 0; rg < 4; rg++)
      gg.ctx[(size_t)(m0 + quad * 4 + rg) * 256 + h * 16 + l16] =
          f2bf(cacc[rg]);
  }
}

// ---------------------------------------------------------------------------
// Grouped LN1 / LN2.
// ---------------------------------------------------------------------------
struct LN1Args {
  const float* r0; const float* r1; const float* r2; const float* r3;
  int s1, s2, s3;
};
__global__ __launch_bounds__(256) void ln1_grouped(
    LN1Args a, const u16* __restrict__ x, u16* __restrict__ out) {
  int row = blockIdx.x, t = threadIdx.x;
  const float* resid;
  int local;
  if (row < a.s1)      { resid = a.r0; local = row; }
  else if (row < a.s2) { resid = a.r1; local = row - a.s1; }
  else if (row < a.s3) { resid = a.r2; local = row - a.s2; }
  else                 { resid = a.r3; local = row - a.s3; }
  float vv = resid[(size_t)local * 256 + t] + bf2f(x[(size_t)row * 256 + t]);
  __shared__ float red[256];
  red[t] = vv;
  __syncthreads();
  for (int s = 128; s > 0; s >>= 1) {
    if (t < s) red[t] += red[t + s];
    __syncthreads();
  }
  float mean = red[0] * (1.0f / 256.0f);
  __syncthreads();
  float d = vv - mean;
  red[t] = d * d;
  __syncthreads();
  for (int s = 128; s > 0; s >>= 1) {
    if (t < s) red[t] += red[t + s];
    __syncthreads();
  }
  float var = red[0] * (1.0f / 256.0f);
  out[(size_t)row * 256 + t] = f2bf(d * rsqrtf(var + 1e-5f));
}

struct LN2Args {
  float* f0; float* f1; u16* b2; u16* b3;
  int s1, s2, s3;
};
__global__ __launch_bounds__(256) void ln2_grouped(
    LN2Args a, const u16* __restrict__ resid, const u16* __restrict__ x) {
  int row = blockIdx.x, t = threadIdx.x;
  float vv = bf2f(resid[(size_t)row * 256 + t]) + bf2f(x[(size_t)row * 256 + t]);
  __shared__ float red[256];
  red[t] = vv;
  __syncthreads();
  for (int s = 128; s > 0; s >>= 1) {
    if (t < s) red[t] += red[t + s];
    __syncthreads();
  }
  float mean = red[0] * (1.0f / 256.0f);
  __syncthreads();
  float d = vv - mean;
  red[t] = d * d;
  __syncthreads();
  for (int s = 128; s > 0; s >>= 1) {
    if (t < s) red[t] += red[t + s];
    __syncthreads();
  }
  float var = red[0] * (1.0f / 256.0f);
  float y = d * rsqrtf(var + 1e-5f);
  if (row < a.s1)
    a.f0[(size_t)row * 256 + t] = y;
  else if (row < a.s2)
    a.f1[(size_t)(row - a.s1) * 256 + t] = y;
  else if (row < a.s3)
    a.b2[(size_t)(row - a.s2) * 512 + t] = f2bf(y);
  else
    a.b3[(size_t)(row - a.s3) * 512 + 256 + t] = f2bf(y);
}

// ---------------------------------------------------------------------------
extern "C" void kernel_launch(void* const* d_in, const int* in_sizes, int n_in,
                              void* d_out, int out_size, void* d_ws, size_t ws_size,
                              hipStream_t stream) {
  const float* ope   = (const float*)d_in[0];
  const float* ma    = (const float*)d_in[1];
  const float* veh   = (const float*)d_in[2];
  const float* proc  = (const float*)d_in[3];
  const float* trans = (const float*)d_in[5];
  const float* mv    = (const float*)d_in[6];
  const int* mask_dyn = (const int*)d_in[7];
  const int* mask_ma  = (const int*)d_in[8];
  const float* Wq = (const float*)d_in[9];
  const float* Wk = (const float*)d_in[10];
  const float* Wv = (const float*)d_in[11];
  const float* Wo = (const float*)d_in[12];
  const float* mixW1 = (const float*)d_in[13];
  const float* mixb1 = (const float*)d_in[14];
  const float* mixW2 = (const float*)d_in[15];
  const float* mixb2 = (const float*)d_in[16];
  const float* ffW1 = (const float*)d_in[17];
  const float* ffb1 = (const float*)d_in[18];
  const float* ffW2 = (const float*)d_in[19];
  const float* ffb2 = (const float*)d_in[20];
  const float* maprojW = (const float*)d_in[21];
  const float* maprojb = (const float*)d_in[22];
  float* out = (float*)d_out;
  char* ws = (char*)d_ws;

  const int OFF[4] = {0, 8192, 9216, 11264};
  const int MS4[4] = {8192, 1024, 2048, 2048};
  const int TOT = 13312;

  const size_t MB = 1 << 20;
  float* A_proc  = (float*)(ws + 0);
  float* A_offb  = (float*)(ws + 4 * MB);
  float* A_pcing = (float*)(ws + 4 * MB + MB / 2);
  float* A_on    = (float*)(ws + 5 * MB + MB / 2);
  u16* ope_bf  = (u16*)(ws + 6 * MB + MB / 2);
  u16* ma_bf   = (u16*)(ws + 10 * MB + MB / 2);
  u16* veh_bf  = (u16*)(ws + 11 * MB + MB / 2);
  u16* WqT     = (u16*)(ws + 12 * MB);
  u16* WkT     = (u16*)(ws + 12 * MB + MB / 2);
  u16* WvT     = (u16*)(ws + 13 * MB);
  u16* WoT     = (u16*)(ws + 13 * MB + MB / 2);
  u16* ffW1T   = (u16*)(ws + 14 * MB);
  u16* ffW2T   = (u16*)(ws + 15 * MB);
  u16* maprojT = (u16*)(ws + 16 * MB);
  u16* q_all   = (u16*)(ws + 16 * MB + MB / 2);   // packed [tile][h][r][d]
  u16* k_all   = (u16*)(ws + 23 * MB);            // packed [g][b][h][c][d]
  u16* v_all   = (u16*)(ws + 27 * MB);
  u16* vT_all  = (u16*)(ws + 31 * MB);
  u16* ctx_all = (u16*)(ws + 35 * MB);
  u16* t1_all  = (u16*)(ws + 41 * MB + MB / 2);
  u16* out1_all= (u16*)(ws + 48 * MB);
  u16* ffh_all = (u16*)(ws + 54 * MB + MB / 2);
  u16* maCat   = (u16*)(ws + 67 * MB + MB / 2);
  unsigned int* mmbuf = (unsigned int*)(ws + 70 * MB);  // [64]

  // init min/max buffer: mins (32 u32) = 0x7F7F7F7F (big float), maxs = 0
  hipMemsetAsync(mmbuf, 0x7F, 128, stream);
  hipMemsetAsync((char*)mmbuf + 128, 0x00, 128, stream);

  // --- prep_a: converts + aproc + min/max partials ---
  {
    PrepArgs pa = {ope, ma, veh, ope_bf, ma_bf, veh_bf,
                   proc, mask_dyn, A_proc, mv, trans, mask_ma, mmbuf};
    prep_a<<<7104, 256, 0, stream>>>(pa);
  }

  // --- weight transposes ---
  {
    TrArgs ta = {Wq, Wk, Wv, Wo, ffW1, ffW2, maprojW,
                 WqT, WkT, WvT, WoT, ffW1T, ffW2T, maprojT};
    transpose_all<<<2176, 256, 0, stream>>>(ta);
  }

  // --- prep_b: normalize aoff/aon + A_pcing ---
  prep_b<<<1536, 256, 0, stream>>>(mv, trans, mask_ma, mmbuf,
                                   A_offb, A_on, A_pcing);

  const size_t MA_OUT  = (size_t)NBATCH * NOPE * EDIM;
  const size_t VEH_OUT = MA_OUT + (size_t)NBATCH * NMA * EDIM;

  const u16* rowbf[4] = {ope_bf, veh_bf, ma_bf, ma_bf};
  const float* costp[4] = {A_proc, A_offb, A_pcing, A_on};

  // --- grouped GEMM #1: q(x4, q-pack) + k(x4, k-pack) + v(x4, row-major) ---
  {
    GGArgs ga; ga.n = 12;
    int wg = 0;
    for (int i = 0; i < 4; i++) {
      ga.g[i] = {rowbf[i], WqT + (size_t)i * 65536, nullptr,
                 q_all + (size_t)OFF[i] * 256, MS4[i], 256, 256, 0, wg, 2, 1};
      wg += (MS4[i] / 128) * 2;
    }
    for (int i = 0; i < 4; i++) {
      ga.g[4 + i] = {ma_bf, WkT + (size_t)i * 65536, nullptr,
                     k_all + (size_t)i * 524288, 2048, 256, 256, 0, wg, 2, 2};
      wg += 32;
    }
    for (int i = 0; i < 4; i++) {
      ga.g[8 + i] = {ma_bf, WvT + (size_t)i * 65536, nullptr,
                     v_all + (size_t)i * 524288, 2048, 256, 256, 0, wg, 2, 0};
      wg += 32;
    }
    gemm_grouped<<<wg, 256, 0, stream>>>(ga);
  }

  transpose_v<<<dim3(8, 4, 64), 256, 0, stream>>>(v_all, vT_all);

  // --- grouped attention: 832 blocks (16-row tiles, XCD-swizzled) ---
  {
    AGArgs aa;
    int wg = 0;
    const int R4[4] = {NOPE, NVEH, NMA, NMA};
    for (int i = 0; i < 4; i++) {
      aa.g[i] = {q_all + (size_t)OFF[i] * 256, k_all + (size_t)i * 524288,
                 vT_all + (size_t)i * 524288, costp[i],
                 ctx_all + (size_t)OFF[i] * 256,
                 mixW1 + (size_t)i * 256, mixb1 + (size_t)i * 128,
                 mixW2 + (size_t)i * 128, mixb2 + (size_t)i * 16,
                 R4[i], wg};
      wg += MS4[i] / 16;
    }
    attn_grouped<<<wg, 256, 0, stream>>>(aa);
  }

  // --- Wo ---
  {
    GGArgs ga; ga.n = 4;
    int wg = 0;
    for (int i = 0; i < 4; i++) {
      ga.g[i] = {ctx_all + (size_t)OFF[i] * 256, WoT + (size_t)i * 65536,
                 nullptr, t1_all + (size_t)OFF[i] * 256,
                 MS4[i], 256, 256, 0, wg, 2, 0};
      wg += (MS4[i] / 128) * 2;
    }
    gemm_grouped<<<wg, 256, 0, stream>>>(ga);
  }

  {
    LN1Args la = {ope, veh, ma, ma, 8192, 9216, 11264};
    ln1_grouped<<<TOT, 256, 0, stream>>>(la, t1_all, out1_all);
  }

  // --- FF1 (bias+relu) ---
  {
    GGArgs ga; ga.n = 4;
    int wg = 0;
    for (int i = 0; i < 4; i++) {
      ga.g[i] = {out1_all + (size_t)OFF[i] * 256, ffW1T + (size_t)i * 131072,
                 ffb1 + (size_t)i * 512, ffh_all + (size_t)OFF[i] * 512,
                 MS4[i], 512, 256, 2, wg, 4, 0};
      wg += (MS4[i] / 128) * 4;
    }
    gemm_grouped<<<wg, 256, 0, stream>>>(ga);
  }

  // --- FF2 (bias) ---
  {
    GGArgs ga; ga.n = 4;
    int wg = 0;
    for (int i = 0; i < 4; i++) {
      ga.g[i] = {ffh_all + (size_t)OFF[i] * 512, ffW2T + (size_t)i * 131072,
                 ffb2 + (size_t)i * 256, t1_all + (size_t)OFF[i] * 256,
                 MS4[i], 256, 512, 1, wg, 2, 0};
      wg += (MS4[i] / 128) * 2;
    }
    gemm_grouped<<<wg, 256, 0, stream>>>(ga);
  }

  {
    LN2Args la = {out, out + VEH_OUT, maCat, maCat, 8192, 9216, 11264};
    ln2_grouped<<<TOT, 256, 0, stream>>>(la, out1_all, t1_all);
  }

  gemm_mfma_f32<<<dim3(2, 16), 256, 0, stream>>>(maCat, maprojT, maprojb,
      out + MA_OUT, 2048, 256, 512);
}

// Round 13
// 275.837 us; speedup vs baseline: 1.1008x; 1.0442x over previous
//
#include <hip/hip_runtime.h>
#include <hip/hip_fp16.h>
#include <hip/hip_bf16.h>

// ---------------------------------------------------------------------------
// EncoderLayer (MatNet mixed-score MHA) for MI355X — R13.
// R13 = R12 + attn TLP fix: R12's attn was latency-bound (occupancy 24%,
// VALU 34%, MFMA 1.6%, HBM 3.8% — 832 blocks = 3.25/CU). Now 2 blocks per
// 16-row tile (8 heads each, 2 heads/wave, unrolled) -> 1664 blocks.
// XCD swizzle kept (b from local&15; wgStarts %16==0).
// Inputs f32, masks int32, d_out f32. Row-space: ope[0,8192) veh[8192,9216)
// ma1[9216,11264) ma2[11264,13312).
// ---------------------------------------------------------------------------

typedef unsigned short u16;
typedef __attribute__((ext_vector_type(8))) short bf16x8;
typedef __attribute__((ext_vector_type(4))) float f32x4;
struct us4 { u16 x, y, z, w; };

__device__ __forceinline__ float bf2f(u16 u) {
  return __uint_as_float(((unsigned int)u) << 16);
}
__device__ __forceinline__ u16 f2bf(float f) {
  unsigned int x = __float_as_uint(f);
  x += 0x7FFFu + ((x >> 16) & 1u);
  return (u16)(x >> 16);
}
// packed fp16 max (ROCm 7.2 lacks the __half2 __hmax2 overload on gfx950)
__device__ __forceinline__ __half2 h2max(__half2 a, __half2 b) {
  unsigned au = *(unsigned*)&a, bu = *(unsigned*)&b, ru;
  asm("v_pk_max_f16 %0, %1, %2" : "=v"(ru) : "v"(au), "v"(bu));
  return *(__half2*)&ru;
}

#define NBATCH 16
#define NOPE   512
#define NMA    128
#define NVEH   64
#define EDIM   256

// ---------------------------------------------------------------------------
// prep_a: [0,2816) f32->bf16 converts; [2816,6912) aproc (2 rows/blk);
// [6912,6976) aoff min/max partials (4 blk/b); [6976,7104) aon min/max
// partials (8 blk/b). mm layout: mins[32] (aoff b, aon 16+b), maxs[32].
// Values are >=0 so float bits compare monotonically as unsigned.
// ---------------------------------------------------------------------------
struct PrepArgs {
  const float* ope; const float* ma; const float* veh;
  u16* ope_bf; u16* ma_bf; u16* veh_bf;
  const float* proc; const int* mask_dyn; float* A_proc;
  const float* mv; const float* trans; const int* mask_ma;
  unsigned int* mm;   // [64]: mins[32], maxs[32]
};
__global__ __launch_bounds__(256) void prep_a(PrepArgs a) {
  int blk = blockIdx.x, t = threadIdx.x;
  if (blk < 2816) {
    int i = blk * 256 + t;
    const float* s; u16* d; int j;
    if (i < 524288)      { s = a.ope; d = a.ope_bf; j = i; }
    else if (i < 655360) { s = a.ma;  d = a.ma_bf;  j = i - 524288; }
    else                 { s = a.veh; d = a.veh_bf; j = i - 655360; }
    float4 v = ((const float4*)s)[j];
    us4 o = { f2bf(v.x), f2bf(v.y), f2bf(v.z), f2bf(v.w) };
    ((us4*)d)[j] = o;
    return;
  }
  if (blk < 6912) {
    int local = blk - 2816;
    int row = local * 2 + (t >> 7);
    int lane = t & 127;
    size_t idx = (size_t)row * NMA + lane;
    float av = a.mask_dyn[idx] ? a.proc[idx] : 0.0f;
    float cand = (av != 0.0f) ? av : 1.0e30f;
    __shared__ float red[256];
    red[t] = cand;
    __syncthreads();
    for (int s = 64; s > 0; s >>= 1) {
      if (lane < s) red[t] = fminf(red[t], red[t + s]);
      __syncthreads();
    }
    float mn = red[t & 128];
    a.A_proc[idx] = (av != 0.0f && av == mn) ? 1.0f : 0.0f;
    return;
  }
  __shared__ float smn[256], smx[256];
  float mn = 1.0e30f, mx = -1.0e30f;
  int mmIdx;
  if (blk < 6976) {
    int local = blk - 6912;
    int b = local >> 2, chunk = local & 3;
    const float* xb = a.mv + (size_t)b * 8192 + chunk * 2048;
#pragma unroll
    for (int r = 0; r < 8; r++) {
      float v = xb[r * 256 + t];
      mn = fminf(mn, v);
      mx = fmaxf(mx, v);
    }
    mmIdx = b;
  } else {
    int local = blk - 6976;
    int b = local >> 3, chunk = local & 7;
    __shared__ unsigned char mrow[NMA];
    if (t < NMA) mrow[t] = (unsigned char)(a.mask_ma[(size_t)b * NMA + t] != 0);
    __syncthreads();
    const float* tb = a.trans + (size_t)b * 16384 + chunk * 2048;
    int rbase = chunk * 16;
#pragma unroll
    for (int r = 0; r < 8; r++) {
      int off = r * 256 + t;
      int row = rbase + (off >> 7), col = off & 127;
      bool m2 = mrow[row] && mrow[col];
      float tt = m2 ? tb[off] : 101.0f;
      mn = fminf(mn, tt);
      mx = fmaxf(mx, tt);
    }
    mmIdx = 16 + b;
  }
  smn[t] = mn; smx[t] = mx;
  __syncthreads();
  for (int s = 128; s > 0; s >>= 1) {
    if (t < s) {
      smn[t] = fminf(smn[t], smn[t + s]);
      smx[t] = fmaxf(smx[t], smx[t + s]);
    }
    __syncthreads();
  }
  if (t == 0) {
    atomicMin(&a.mm[mmIdx], __float_as_uint(smn[0]));
    atomicMax(&a.mm[32 + mmIdx], __float_as_uint(smx[0]));
  }
}

// ---------------------------------------------------------------------------
// prep_b: [0,512) aoff normalize; [512,1536) aon normalize + A_pcing.
// ---------------------------------------------------------------------------
__global__ __launch_bounds__(256) void prep_b(
    const float* __restrict__ mv, const float* __restrict__ trans,
    const int* __restrict__ mask_ma, const unsigned int* __restrict__ mm,
    float* __restrict__ A_offb, float* __restrict__ a_on,
    float* __restrict__ a_pcing) {
  int blk = blockIdx.x, t = threadIdx.x;
  if (blk < 512) {
    int b = blk >> 5, off = (blk & 31) * 256 + t;
    float lo = __uint_as_float(mm[b]);
    float inv = 1.0f / (__uint_as_float(mm[32 + b]) - lo);
    size_t idx = (size_t)b * 8192 + off;
    A_offb[idx] = 1.0f - (mv[idx] - lo) * inv;
    return;
  }
  int local = blk - 512;
  int b = local >> 6, off = (local & 63) * 256 + t;
  int row = off >> 7, col = off & 127;
  bool m2 = (mask_ma[(size_t)b * NMA + row] != 0) &&
            (mask_ma[(size_t)b * NMA + col] != 0);
  size_t idx = (size_t)b * 16384 + off;
  float tt = m2 ? trans[idx] : 101.0f;
  float lo = __uint_as_float(mm[16 + b]);
  float inv = 1.0f / (__uint_as_float(mm[48 + b]) - lo);
  a_on[idx] = 1.0f - (tt - lo) * inv;
  a_pcing[idx] = m2 ? 0.0f : 1.0f;
}

// ---------------------------------------------------------------------------
// Merged weight transposes: f32 [Kd][Nd] -> bf16 [Nd][Kd], 32x32 tiles.
// ---------------------------------------------------------------------------
struct TrArgs {
  const float* Wq; const float* Wk; const float* Wv; const float* Wo;
  const float* ffW1; const float* ffW2; const float* maproj;
  u16* WqT; u16* WkT; u16* WvT; u16* WoT; u16* ffW1T; u16* ffW2T; u16* maprojT;
};
__global__ __launch_bounds__(256) void transpose_all(TrArgs a) {
  int blk = blockIdx.x;
  const float* src; u16* dst; int Kd, Nd, tile;
  if (blk < 1024) {
    int w = blk >> 8, i = (blk >> 6) & 3; tile = blk & 63;
    const float* sw = (w == 0 ? a.Wq : w == 1 ? a.Wk : w == 2 ? a.Wv : a.Wo);
    u16* dw = (w == 0 ? a.WqT : w == 1 ? a.WkT : w == 2 ? a.WvT : a.WoT);
    src = sw + (size_t)i * 65536; dst = dw + (size_t)i * 65536;
    Kd = 256; Nd = 256;
  } else if (blk < 1536) {
    int z = (blk - 1024) >> 7; tile = (blk - 1024) & 127;
    src = a.ffW1 + (size_t)z * 131072; dst = a.ffW1T + (size_t)z * 131072;
    Kd = 256; Nd = 512;
  } else {
    int z = (blk - 1536) >> 7; tile = (blk - 1536) & 127;
    if (z < 4) { src = a.ffW2 + (size_t)z * 131072; dst = a.ffW2T + (size_t)z * 131072; }
    else       { src = a.maproj; dst = a.maprojT; }
    Kd = 512; Nd = 256;
  }
  int nx = Nd >> 5;
  int k0 = (tile / nx) * 32, n0 = (tile % nx) * 32;
  __shared__ float tl[32][33];
  int tx = threadIdx.x & 31, ty = threadIdx.x >> 5;
#pragma unroll
  for (int r = 0; r < 4; r++)
    tl[ty + r * 8][tx] = src[(size_t)(k0 + ty + r * 8) * Nd + n0 + tx];
  __syncthreads();
#pragma unroll
  for (int r = 0; r < 4; r++)
    dst[(size_t)(n0 + ty + r * 8) * Kd + k0 + tx] = f2bf(tl[tx][ty + r * 8]);
}

// ---------------------------------------------------------------------------
// v_all [4][16 b][128 c][256 d] -> vT_all [4][16 b][256 d][128 c], bf16.
// ---------------------------------------------------------------------------
__global__ __launch_bounds__(256) void transpose_v(
    const u16* __restrict__ src, u16* __restrict__ dst) {
  int g = blockIdx.z >> 4, b = blockIdx.z & 15;
  int d0 = blockIdx.x * 32, c0 = blockIdx.y * 32;
  __shared__ u16 tile[32][33];
  int tx = threadIdx.x & 31, ty = threadIdx.x >> 5;
  const u16* s = src + ((size_t)g * 16 + b) * 32768;
  u16* d = dst + ((size_t)g * 16 + b) * 32768;
#pragma unroll
  for (int r = 0; r < 4; r++)
    tile[ty + r * 8][tx] = s[(size_t)(c0 + ty + r * 8) * 256 + d0 + tx];
  __syncthreads();
#pragma unroll
  for (int r = 0; r < 4; r++)
    d[(size_t)(d0 + ty + r * 8) * 128 + c0 + tx] = tile[tx][ty + r * 8];
}

// ---------------------------------------------------------------------------
// Grouped MFMA GEMM. mode: 0 = row-major C, 1 = q-pack C[tile][h][r][d16],
// 2 = k-pack C[b][h][c][d16].
// ---------------------------------------------------------------------------
struct GG {
  const u16* A; const u16* WT; const float* bias; u16* C;
  int M, N, K, epi, wgStart, wgCols, mode;
};
struct GGArgs { GG g[12]; int n; };

__global__ __launch_bounds__(256) void gemm_grouped(GGArgs args) {
  int wg = blockIdx.x;
  int gi = 0;
  for (int i = 1; i < args.n; i++)
    if (wg >= args.g[i].wgStart) gi = i;
  GG gg = args.g[gi];
  int lwg = wg - gg.wgStart;
  int bx = lwg & (gg.wgCols - 1);
  int by = lwg >> ((gg.wgCols == 2) ? 1 : 2);
  int N = gg.N, K = gg.K;

  __shared__ u16 As[128][40];
  __shared__ u16 Bs[128][40];
  int tid = threadIdx.x;
  int lane = tid & 63, wid = tid >> 6;
  int wr = (wid >> 1) * 64, wc = (wid & 1) * 64;
  int m16 = lane & 15, quad = lane >> 4;
  int rb = by * 128, cb = bx * 128;
  int srow = tid >> 2;
  int schunk = (tid & 3) * 8;

  f32x4 acc[4][4];
#pragma unroll
  for (int i = 0; i < 4; i++)
#pragma unroll
    for (int j = 0; j < 4; j++) acc[i][j] = (f32x4){0.f, 0.f, 0.f, 0.f};

  for (int k0 = 0; k0 < K; k0 += 32) {
    uint4 va0 = *(const uint4*)(gg.A + (size_t)(rb + srow) * K + k0 + schunk);
    uint4 va1 = *(const uint4*)(gg.A + (size_t)(rb + 64 + srow) * K + k0 + schunk);
    uint4 vb0 = *(const uint4*)(gg.WT + (size_t)(cb + srow) * K + k0 + schunk);
    uint4 vb1 = *(const uint4*)(gg.WT + (size_t)(cb + 64 + srow) * K + k0 + schunk);
    __syncthreads();
    *(uint4*)&As[srow][schunk] = va0;
    *(uint4*)&As[64 + srow][schunk] = va1;
    *(uint4*)&Bs[srow][schunk] = vb0;
    *(uint4*)&Bs[64 + srow][schunk] = vb1;
    __syncthreads();
    bf16x8 af[4], bfr[4];
#pragma unroll
    for (int i = 0; i < 4; i++)
      af[i] = *(const bf16x8*)&As[wr + i * 16 + m16][quad * 8];
#pragma unroll
    for (int j = 0; j < 4; j++)
      bfr[j] = *(const bf16x8*)&Bs[wc + j * 16 + m16][quad * 8];
#pragma unroll
    for (int i = 0; i < 4; i++)
#pragma unroll
      for (int j = 0; j < 4; j++)
        acc[i][j] = __builtin_amdgcn_mfma_f32_16x16x32_bf16(
            af[i], bfr[j], acc[i][j], 0, 0, 0);
  }

#pragma unroll
  for (int i = 0; i < 4; i++) {
#pragma unroll
    for (int j = 0; j < 4; j++) {
      int col = cb + wc + j * 16 + m16;
      float bv = (gg.epi >= 1) ? gg.bias[col] : 0.0f;
#pragma unroll
      for (int r = 0; r < 4; r++) {
        int row = rb + wr + i * 16 + quad * 4 + r;
        float v = acc[i][j][r] + bv;
        if (gg.epi == 2) v = fmaxf(v, 0.0f);
        size_t off;
        if (gg.mode == 0) {
          off = (size_t)row * N + col;
        } else if (gg.mode == 1) {          // q-pack: [row>>4][h][r16][d16]
          off = ((size_t)(row >> 4)) * 4096 + (size_t)(col >> 4) * 256 +
                (size_t)(row & 15) * 16 + (col & 15);
        } else {                            // k-pack: [b][h][c][d16]
          off = ((size_t)(row >> 7)) * 32768 + (size_t)(col >> 4) * 2048 +
                (size_t)(row & 127) * 16 + (col & 15);
        }
        gg.C[off] = f2bf(v);
      }
    }
  }
}

// ---------------------------------------------------------------------------
// Plain MFMA GEMM with f32 output (final ma-projection).
// ---------------------------------------------------------------------------
__global__ __launch_bounds__(256) void gemm_mfma_f32(
    const u16* __restrict__ A, const u16* __restrict__ WT,
    const float* __restrict__ bias, float* __restrict__ C,
    int M, int N, int K) {
  __shared__ u16 As[128][40];
  __shared__ u16 Bs[128][40];
  int tid = threadIdx.x;
  int lane = tid & 63, wid = tid >> 6;
  int wr = (wid >> 1) * 64, wc = (wid & 1) * 64;
  int m16 = lane & 15, quad = lane >> 4;
  int rb = blockIdx.y * 128, cb = blockIdx.x * 128;
  int srow = tid >> 2;
  int schunk = (tid & 3) * 8;
  f32x4 acc[4][4];
#pragma unroll
  for (int i = 0; i < 4; i++)
#pragma unroll
    for (int j = 0; j < 4; j++) acc[i][j] = (f32x4){0.f, 0.f, 0.f, 0.f};
  for (int k0 = 0; k0 < K; k0 += 32) {
    uint4 va0 = *(const uint4*)(A + (size_t)(rb + srow) * K + k0 + schunk);
    uint4 va1 = *(const uint4*)(A + (size_t)(rb + 64 + srow) * K + k0 + schunk);
    uint4 vb0 = *(const uint4*)(WT + (size_t)(cb + srow) * K + k0 + schunk);
    uint4 vb1 = *(const uint4*)(WT + (size_t)(cb + 64 + srow) * K + k0 + schunk);
    __syncthreads();
    *(uint4*)&As[srow][schunk] = va0;
    *(uint4*)&As[64 + srow][schunk] = va1;
    *(uint4*)&Bs[srow][schunk] = vb0;
    *(uint4*)&Bs[64 + srow][schunk] = vb1;
    __syncthreads();
    bf16x8 af[4], bfr[4];
#pragma unroll
    for (int i = 0; i < 4; i++)
      af[i] = *(const bf16x8*)&As[wr + i * 16 + m16][quad * 8];
#pragma unroll
    for (int j = 0; j < 4; j++)
      bfr[j] = *(const bf16x8*)&Bs[wc + j * 16 + m16][quad * 8];
#pragma unroll
    for (int i = 0; i < 4; i++)
#pragma unroll
      for (int j = 0; j < 4; j++)
        acc[i][j] = __builtin_amdgcn_mfma_f32_16x16x32_bf16(
            af[i], bfr[j], acc[i][j], 0, 0, 0);
  }
#pragma unroll
  for (int i = 0; i < 4; i++)
#pragma unroll
    for (int j = 0; j < 4; j++) {
      int col = cb + wc + j * 16 + m16;
      float bv = bias[col];
#pragma unroll
      for (int r = 0; r < 4; r++) {
        int row = rb + wr + i * 16 + quad * 4 + r;
        C[(size_t)row * N + col] = acc[i][j][r] + bv;
      }
    }
}

// ---------------------------------------------------------------------------
// Grouped fused MFMA attention, R13: 2 blocks per 16-row tile (8 heads each,
// 2 heads/wave unrolled) -> 1664 blocks for TLP. XCD swizzle: b from
// local&15 (wgStarts %16==0), hgrp from bit4, tile from local>>5.
// q/k per-head-packed; cost staged once per block as fp16.
// ---------------------------------------------------------------------------
struct AG {
  const u16* q; const u16* k; const u16* vT; const float* cost; u16* ctx;
  const float* w1; const float* b1; const float* w2; const float* b2;
  int R, wgStart;
};
struct AGArgs { AG g[4]; };

#define CSTRIDE 134   // halves; <=2-way LDS banks on half2 reads

__global__ __launch_bounds__(256) void attn_grouped(AGArgs args) {
  int blk = blockIdx.x;
  int gi = 0;
#pragma unroll
  for (int i = 1; i < 4; i++)
    if (blk >= args.g[i].wgStart) gi = i;
  AG gg = args.g[gi];
  int local = blk - gg.wgStart;

  int t = threadIdx.x;
  int wave = t >> 6, lane = t & 63;
  int quad = lane >> 4, l16 = lane & 15;
  // XCD swizzle: j = local&15 -> b; hgrp = bit4; tile = local>>5.
  int j = local & 15;
  int b = (j & 7) * 2 + (j >> 3);
  int hgrp = (local >> 4) & 1;
  int tile = local >> 5;
  int m0 = b * gg.R + tile * 16;

  __shared__ __half costs_h[16 * CSTRIDE];
  __shared__ u16 pbuf[4][16 * 136];

  const float* cp = gg.cost + (size_t)m0 * 128;
  for (int i = t; i < 2048; i += 256)
    costs_h[(i >> 7) * CSTRIDE + (i & 127)] = __float2half(cp[i]);
  __syncthreads();

  const bf16x8 zerof = (bf16x8){0, 0, 0, 0, 0, 0, 0, 0};
  const f32x4 zacc = (f32x4){0.f, 0.f, 0.f, 0.f};
  const __half2 zh = __float2half2_rn(0.0f);
  u16* pb = pbuf[wave];
  const u16* qtile = gg.q + ((size_t)(m0 >> 4)) * 4096;   // [h][r16][d16]
  const u16* kb    = gg.k + (size_t)b * 32768;            // [h][c128][d16]

#pragma unroll
  for (int hh = 0; hh < 2; hh++) {
    int h = hgrp * 8 + wave * 2 + hh;

    __half2 w10h[8], w11h[8], b1h[8], w2h[8];
#pragma unroll
    for (int s = 0; s < 8; s++) {
      w10h[s] = __float2half2_rn(gg.w1[h * 16 + s] * 0.25f);
      w11h[s] = __float2half2_rn(gg.w1[h * 16 + 8 + s]);
      b1h[s]  = __float2half2_rn(gg.b1[h * 8 + s]);
      w2h[s]  = __float2half2_rn(gg.w2[h * 8 + s]);
    }
    float wb2v = gg.b2[h];

    bf16x8 bq = zerof;
    if (quad < 2)
      bq = *(const bf16x8*)(qtile + (size_t)h * 256 + l16 * 16 + quad * 8);
    f32x4 st[8];
#pragma unroll
    for (int ct = 0; ct < 8; ct++) {
      bf16x8 ak = zerof;
      if (quad < 2)
        ak = *(const bf16x8*)(kb + (size_t)h * 2048 + (ct * 16 + l16) * 16 +
                              quad * 8);
      st[ct] = __builtin_amdgcn_mfma_f32_16x16x32_bf16(ak, bq, zacc, 0, 0, 0);
    }

#pragma unroll
    for (int ct = 0; ct < 8; ct++) {
#pragma unroll
      for (int p = 0; p < 2; p++) {
        __half2 d2 = __float22half2_rn(
            make_float2(st[ct][p * 2], st[ct][p * 2 + 1]));
        __half2 c2 = *(const __half2*)&costs_h[l16 * CSTRIDE + ct * 16 +
                                               quad * 4 + p * 2];
        __half2 s2 = zh;
#pragma unroll
        for (int s = 0; s < 8; s++) {
          __half2 hm = __hfma2(d2, w10h[s], __hfma2(c2, w11h[s], b1h[s]));
          hm = h2max(hm, zh);
          s2 = __hfma2(hm, w2h[s], s2);
        }
        float2 sf = __half22float2(s2);
        st[ct][p * 2]     = sf.x + wb2v;
        st[ct][p * 2 + 1] = sf.y + wb2v;
      }
    }

    float mx = -1.0e30f;
#pragma unroll
    for (int ct = 0; ct < 8; ct++)
#pragma unroll
      for (int rg = 0; rg < 4; rg++) mx = fmaxf(mx, st[ct][rg]);
    mx = fmaxf(mx, __shfl_xor(mx, 16, 64));
    mx = fmaxf(mx, __shfl_xor(mx, 32, 64));
    float sum = 0.0f;
#pragma unroll
    for (int ct = 0; ct < 8; ct++)
#pragma unroll
      for (int rg = 0; rg < 4; rg++) {
        float e = __expf(st[ct][rg] - mx);
        st[ct][rg] = e;
        sum += e;
      }
    sum += __shfl_xor(sum, 16, 64);
    sum += __shfl_xor(sum, 32, 64);
    float inv = 1.0f / sum;

#pragma unroll
    for (int ct = 0; ct < 8; ct++) {
#pragma unroll
      for (int p = 0; p < 2; p++) {
        __hip_bfloat162 pk = __float22bfloat162_rn(
            make_float2(st[ct][p * 2] * inv, st[ct][p * 2 + 1] * inv));
        *(unsigned int*)&pb[l16 * 136 + ct * 16 + quad * 4 + p * 2] =
            *(unsigned int*)&pk;
      }
    }

    f32x4 cacc = zacc;
#pragma unroll
    for (int ks = 0; ks < 4; ks++) {
      bf16x8 ap = *(const bf16x8*)&pb[l16 * 136 + ks * 32 + quad * 8];
      bf16x8 bv = *(const bf16x8*)(gg.vT + (size_t)b * 32768 +
                                   (size_t)(h * 16 + l16) * 128 + ks * 32 +
                                   quad * 8);
      cacc = __builtin_amdgcn_mfma_f32_16x16x32_bf16(ap, bv, cacc, 0, 0, 0);
    }

#pragma unroll
    for (int rg = 0; rg < 4; rg++)
      gg.ctx[(size_t)(m0 + quad * 4 + rg) * 256 + h * 16 + l16] =
          f2bf(cacc[rg]);
  }
}

// ---------------------------------------------------------------------------
// Grouped LN1 / LN2.
// ---------------------------------------------------------------------------
struct LN1Args {
  const float* r0; const float* r1; const float* r2; const float* r3;
  int s1, s2, s3;
};
__global__ __launch_bounds__(256) void ln1_grouped(
    LN1Args a, const u16* __restrict__ x, u16* __restrict__ out) {
  int row = blockIdx.x, t = threadIdx.x;
  const float* resid;
  int local;
  if (row < a.s1)      { resid = a.r0; local = row; }
  else if (row < a.s2) { resid = a.r1; local = row - a.s1; }
  else if (row < a.s3) { resid = a.r2; local = row - a.s2; }
  else                 { resid = a.r3; local = row - a.s3; }
  float vv = resid[(size_t)local * 256 + t] + bf2f(x[(size_t)row * 256 + t]);
  __shared__ float red[256];
  red[t] = vv;
  __syncthreads();
  for (int s = 128; s > 0; s >>= 1) {
    if (t < s) red[t] += red[t + s];
    __syncthreads();
  }
  float mean = red[0] * (1.0f / 256.0f);
  __syncthreads();
  float d = vv - mean;
  red[t] = d * d;
  __syncthreads();
  for (int s = 128; s > 0; s >>= 1) {
    if (t < s) red[t] += red[t + s];
    __syncthreads();
  }
  float var = red[0] * (1.0f / 256.0f);
  out[(size_t)row * 256 + t] = f2bf(d * rsqrtf(var + 1e-5f));
}

struct LN2Args {
  float* f0; float* f1; u16* b2; u16* b3;
  int s1, s2, s3;
};
__global__ __launch_bounds__(256) void ln2_grouped(
    LN2Args a, const u16* __restrict__ resid, const u16* __restrict__ x) {
  int row = blockIdx.x, t = threadIdx.x;
  float vv = bf2f(resid[(size_t)row * 256 + t]) + bf2f(x[(size_t)row * 256 + t]);
  __shared__ float red[256];
  red[t] = vv;
  __syncthreads();
  for (int s = 128; s > 0; s >>= 1) {
    if (t < s) red[t] += red[t + s];
    __syncthreads();
  }
  float mean = red[0] * (1.0f / 256.0f);
  __syncthreads();
  float d = vv - mean;
  red[t] = d * d;
  __syncthreads();
  for (int s = 128; s > 0; s >>= 1) {
    if (t < s) red[t] += red[t + s];
    __syncthreads();
  }
  float var = red[0] * (1.0f / 256.0f);
  float y = d * rsqrtf(var + 1e-5f);
  if (row < a.s1)
    a.f0[(size_t)row * 256 + t] = y;
  else if (row < a.s2)
    a.f1[(size_t)(row - a.s1) * 256 + t] = y;
  else if (row < a.s3)
    a.b2[(size_t)(row - a.s2) * 512 + t] = f2bf(y);
  else
    a.b3[(size_t)(row - a.s3) * 512 + 256 + t] = f2bf(y);
}

// ---------------------------------------------------------------------------
extern "C" void kernel_launch(void* const* d_in, const int* in_sizes, int n_in,
                              void* d_out, int out_size, void* d_ws, size_t ws_size,
                              hipStream_t stream) {
  const float* ope   = (const float*)d_in[0];
  const float* ma    = (const float*)d_in[1];
  const float* veh   = (const float*)d_in[2];
  const float* proc  = (const float*)d_in[3];
  const float* trans = (const float*)d_in[5];
  const float* mv    = (const float*)d_in[6];
  const int* mask_dyn = (const int*)d_in[7];
  const int* mask_ma  = (const int*)d_in[8];
  const float* Wq = (const float*)d_in[9];
  const float* Wk = (const float*)d_in[10];
  const float* Wv = (const float*)d_in[11];
  const float* Wo = (const float*)d_in[12];
  const float* mixW1 = (const float*)d_in[13];
  const float* mixb1 = (const float*)d_in[14];
  const float* mixW2 = (const float*)d_in[15];
  const float* mixb2 = (const float*)d_in[16];
  const float* ffW1 = (const float*)d_in[17];
  const float* ffb1 = (const float*)d_in[18];
  const float* ffW2 = (const float*)d_in[19];
  const float* ffb2 = (const float*)d_in[20];
  const float* maprojW = (const float*)d_in[21];
  const float* maprojb = (const float*)d_in[22];
  float* out = (float*)d_out;
  char* ws = (char*)d_ws;

  const int OFF[4] = {0, 8192, 9216, 11264};
  const int MS4[4] = {8192, 1024, 2048, 2048};
  const int TOT = 13312;

  const size_t MB = 1 << 20;
  float* A_proc  = (float*)(ws + 0);
  float* A_offb  = (float*)(ws + 4 * MB);
  float* A_pcing = (float*)(ws + 4 * MB + MB / 2);
  float* A_on    = (float*)(ws + 5 * MB + MB / 2);
  u16* ope_bf  = (u16*)(ws + 6 * MB + MB / 2);
  u16* ma_bf   = (u16*)(ws + 10 * MB + MB / 2);
  u16* veh_bf  = (u16*)(ws + 11 * MB + MB / 2);
  u16* WqT     = (u16*)(ws + 12 * MB);
  u16* WkT     = (u16*)(ws + 12 * MB + MB / 2);
  u16* WvT     = (u16*)(ws + 13 * MB);
  u16* WoT     = (u16*)(ws + 13 * MB + MB / 2);
  u16* ffW1T   = (u16*)(ws + 14 * MB);
  u16* ffW2T   = (u16*)(ws + 15 * MB);
  u16* maprojT = (u16*)(ws + 16 * MB);
  u16* q_all   = (u16*)(ws + 16 * MB + MB / 2);   // packed [tile][h][r][d]
  u16* k_all   = (u16*)(ws + 23 * MB);            // packed [g][b][h][c][d]
  u16* v_all   = (u16*)(ws + 27 * MB);
  u16* vT_all  = (u16*)(ws + 31 * MB);
  u16* ctx_all = (u16*)(ws + 35 * MB);
  u16* t1_all  = (u16*)(ws + 41 * MB + MB / 2);
  u16* out1_all= (u16*)(ws + 48 * MB);
  u16* ffh_all = (u16*)(ws + 54 * MB + MB / 2);
  u16* maCat   = (u16*)(ws + 67 * MB + MB / 2);
  unsigned int* mmbuf = (unsigned int*)(ws + 70 * MB);  // [64]

  // init min/max buffer: mins (32 u32) = 0x7F7F7F7F (big float), maxs = 0
  hipMemsetAsync(mmbuf, 0x7F, 128, stream);
  hipMemsetAsync((char*)mmbuf + 128, 0x00, 128, stream);

  // --- prep_a: converts + aproc + min/max partials ---
  {
    PrepArgs pa = {ope, ma, veh, ope_bf, ma_bf, veh_bf,
                   proc, mask_dyn, A_proc, mv, trans, mask_ma, mmbuf};
    prep_a<<<7104, 256, 0, stream>>>(pa);
  }

  // --- weight transposes ---
  {
    TrArgs ta = {Wq, Wk, Wv, Wo, ffW1, ffW2, maprojW,
                 WqT, WkT, WvT, WoT, ffW1T, ffW2T, maprojT};
    transpose_all<<<2176, 256, 0, stream>>>(ta);
  }

  // --- prep_b: normalize aoff/aon + A_pcing ---
  prep_b<<<1536, 256, 0, stream>>>(mv, trans, mask_ma, mmbuf,
                                   A_offb, A_on, A_pcing);

  const size_t MA_OUT  = (size_t)NBATCH * NOPE * EDIM;
  const size_t VEH_OUT = MA_OUT + (size_t)NBATCH * NMA * EDIM;

  const u16* rowbf[4] = {ope_bf, veh_bf, ma_bf, ma_bf};
  const float* costp[4] = {A_proc, A_offb, A_pcing, A_on};

  // --- grouped GEMM #1: q(x4, q-pack) + k(x4, k-pack) + v(x4, row-major) ---
  {
    GGArgs ga; ga.n = 12;
    int wg = 0;
    for (int i = 0; i < 4; i++) {
      ga.g[i] = {rowbf[i], WqT + (size_t)i * 65536, nullptr,
                 q_all + (size_t)OFF[i] * 256, MS4[i], 256, 256, 0, wg, 2, 1};
      wg += (MS4[i] / 128) * 2;
    }
    for (int i = 0; i < 4; i++) {
      ga.g[4 + i] = {ma_bf, WkT + (size_t)i * 65536, nullptr,
                     k_all + (size_t)i * 524288, 2048, 256, 256, 0, wg, 2, 2};
      wg += 32;
    }
    for (int i = 0; i < 4; i++) {
      ga.g[8 + i] = {ma_bf, WvT + (size_t)i * 65536, nullptr,
                     v_all + (size_t)i * 524288, 2048, 256, 256, 0, wg, 2, 0};
      wg += 32;
    }
    gemm_grouped<<<wg, 256, 0, stream>>>(ga);
  }

  transpose_v<<<dim3(8, 4, 64), 256, 0, stream>>>(v_all, vT_all);

  // --- grouped attention: 1664 blocks (2 per 16-row tile, XCD-swizzled) ---
  {
    AGArgs aa;
    int wg = 0;
    const int R4[4] = {NOPE, NVEH, NMA, NMA};
    for (int i = 0; i < 4; i++) {
      aa.g[i] = {q_all + (size_t)OFF[i] * 256, k_all + (size_t)i * 524288,
                 vT_all + (size_t)i * 524288, costp[i],
                 ctx_all + (size_t)OFF[i] * 256,
                 mixW1 + (size_t)i * 256, mixb1 + (size_t)i * 128,
                 mixW2 + (size_t)i * 128, mixb2 + (size_t)i * 16,
                 R4[i], wg};
      wg += MS4[i] / 8;
    }
    attn_grouped<<<wg, 256, 0, stream>>>(aa);
  }

  // --- Wo ---
  {
    GGArgs ga; ga.n = 4;
    int wg = 0;
    for (int i = 0; i < 4; i++) {
      ga.g[i] = {ctx_all + (size_t)OFF[i] * 256, WoT + (size_t)i * 65536,
                 nullptr, t1_all + (size_t)OFF[i] * 256,
                 MS4[i], 256, 256, 0, wg, 2, 0};
      wg += (MS4[i] / 128) * 2;
    }
    gemm_grouped<<<wg, 256, 0, stream>>>(ga);
  }

  {
    LN1Args la = {ope, veh, ma, ma, 8192, 9216, 11264};
    ln1_grouped<<<TOT, 256, 0, stream>>>(la, t1_all, out1_all);
  }

  // --- FF1 (bias+relu) ---
  {
    GGArgs ga; ga.n = 4;
    int wg = 0;
    for (int i = 0; i < 4; i++) {
      ga.g[i] = {out1_all + (size_t)OFF[i] * 256, ffW1T + (size_t)i * 131072,
                 ffb1 + (size_t)i * 512, ffh_all + (size_t)OFF[i] * 512,
                 MS4[i], 512, 256, 2, wg, 4, 0};
      wg += (MS4[i] / 128) * 4;
    }
    gemm_grouped<<<wg, 256, 0, stream>>>(ga);
  }

  // --- FF2 (bias) ---
  {
    GGArgs ga; ga.n = 4;
    int wg = 0;
    for (int i = 0; i < 4; i++) {
      ga.g[i] = {ffh_all + (size_t)OFF[i] * 512, ffW2T + (size_t)i * 131072,
                 ffb2 + (size_t)i * 256, t1_all + (size_t)OFF[i] * 256,
                 MS4[i], 256, 512, 1, wg, 2, 0};
      wg += (MS4[i] / 128) * 2;
    }
    gemm_grouped<<<wg, 256, 0, stream>>>(ga);
  }

  {
    LN2Args la = {out, out + VEH_OUT, maCat, maCat, 8192, 9216, 11264};
    ln2_grouped<<<TOT, 256, 0, stream>>>(la, out1_all, t1_all);
  }

  gemm_mfma_f32<<<dim3(2, 16), 256, 0, stream>>>(maCat, maprojT, maprojb,
      out + MA_OUT, 2048, 256, 512);
}